// Round 5
// baseline (320.286 us; speedup 1.0000x reference)
//
#include <hip/hip_runtime.h>
#include <math.h>

#define AS1 __attribute__((address_space(1)))
#define AS3 __attribute__((address_space(3)))

typedef __attribute__((ext_vector_type(8))) short short8;
typedef __attribute__((ext_vector_type(4))) float f32x4;

#define WAITV(n) asm volatile("s_waitcnt vmcnt(" #n ")" ::: "memory")
#define BARRIER() asm volatile("s_barrier" ::: "memory")

static __device__ __forceinline__ unsigned short f2bf(float f) {
    unsigned u = __float_as_uint(f);
    unsigned r = (u + 0x7fffu + ((u >> 16) & 1u)) >> 16;
    return (unsigned short)r;
}

// ---------------- f32 -> bf16 convert (vectorized x4) ----------------
__global__ __launch_bounds__(256) void cvt_f32_bf16(const float* __restrict__ src,
                                                    unsigned short* __restrict__ dst,
                                                    int n4) {
    int i = blockIdx.x * 256 + threadIdx.x;
    int stride = gridDim.x * 256;
    for (; i < n4; i += stride) {
        float4 v = ((const float4*)src)[i];
        ushort4 o;
        o.x = f2bf(v.x); o.y = f2bf(v.y); o.z = f2bf(v.z); o.w = f2bf(v.w);
        ((ushort4*)dst)[i] = o;
    }
}

// extract ts (cols 0..127 of ssm_p, row stride 160) -> dense bf16 1024x128
__global__ __launch_bounds__(256) void cvt_ts(const float* __restrict__ ssmp,
                                              unsigned short* __restrict__ ts) {
    int i = blockIdx.x * 256 + threadIdx.x;   // < 32768
    int t = i >> 5, c4 = (i & 31) * 4;
    float4 v = *(const float4*)&ssmp[t * 160 + c4];
    ushort4 o;
    o.x = f2bf(v.x); o.y = f2bf(v.y); o.z = f2bf(v.z); o.w = f2bf(v.w);
    *(ushort4*)&ts[t * 128 + c4] = o;
}

// ---------------- depthwise causal conv (K=4) + bias + silu ----------------
__global__ __launch_bounds__(256) void conv_silu(const float* __restrict__ h,
                                                 const float* __restrict__ cw,
                                                 const float* __restrict__ cb,
                                                 float* __restrict__ hc_f,
                                                 unsigned short* __restrict__ hc_bf) {
    int idx = blockIdx.x * 256 + threadIdx.x;   // < 1024*4096
    int d = idx & 4095, t = idx >> 12;
    float acc = cb[d];
    float4 w = *(const float4*)&cw[d * 4];
    const float* wp = (const float*)&w;
#pragma unroll
    for (int k = 0; k < 4; ++k) {
        int tt = t + k - 3;
        if (tt >= 0) acc += h[tt * 4096 + d] * wp[k];
    }
    float s = acc / (1.f + __expf(-acc));   // silu
    hc_f[idx] = s;
    hc_bf[idx] = f2bf(s);
}

// ======== pipelined 256x256 bf16 MFMA GEMM: C = A(M,K) @ B(N,K)^T ========
// BM=BN=256, BK=64. 512 threads = 8 waves (2M x 4N), wave tile 128x64
// (m201 geometry: 24KB LDS-read per wave per K-tile vs 614 MFMA-cyc/SIMD —
// balanced, unlike 64x64 wave tiles which are 2x LDS-read-bound).
// Double-buffered 128KB LDS, counted vmcnt(8), raw s_barrier, XOR-swizzled
// LDS via pre-swizzled global source (linear dest for global_load_lds),
// setprio around MFMA quadrants, XCD-bijective swizzle. Split-K -> f32
// atomicAdd epilogues into zeroed outputs. M fixed = 1024 (4 tile rows).
enum { G_SPLIT = 0, G_ATOMIC = 1 };

template <int EPI>
__global__ __launch_bounds__(512, 2)
void gemm256(const short* __restrict__ A, const short* __restrict__ B,
             float* __restrict__ C0, float* __restrict__ C1,
             int N, int K, int kchunk) {
    __shared__ short lds[2 * 32768];   // per buf: A 256x64 (16384) + B 256x64

    const int tid = threadIdx.x;
    const int wv = tid >> 6, ln = tid & 63;
    const int lr = ln & 15, kg = ln >> 4;
    const int wm = wv >> 2, wn = wv & 3;

    const int nwg = gridDim.x;
    const int bid = blockIdx.x;
    const int swz = (bid & 7) * (nwg >> 3) + (bid >> 3);   // nwg % 8 == 0
    const int by = swz & 3, bx = swz >> 2;                 // M/256 = 4 always
    const int m0 = by * 256, n0 = bx * 256;
    const int kbeg = blockIdx.z * kchunk;
    const int NT = kchunk >> 6;

    f32x4 acc[8][4];
#pragma unroll
    for (int mi = 0; mi < 8; ++mi)
#pragma unroll
        for (int ni = 0; ni < 4; ++ni) acc[mi][ni] = (f32x4){0.f, 0.f, 0.f, 0.f};

    const short* Abase = A + (size_t)m0 * K + kbeg;
    const short* Bbase = B + (size_t)n0 * K + kbeg;

    // Stage K-tile kt into buffer b: 4 passes A + 4 passes B, 8 gload/thread.
    // LDS dest linear; source column pre-swizzled so that after the write,
    // LDS[row][col ^ ((row&7)<<3)] = Global[row][col]   (rule 21).
#define STAGE(kt, b)                                                          \
    {                                                                         \
        short* lbase = &lds[(b) * 32768];                                     \
        _Pragma("unroll")                                                     \
        for (int r = 0; r < 4; ++r) {                                         \
            int c = r * 512 + tid;                                            \
            int row = c >> 3, cb8 = (c & 7) << 4;                             \
            int scb = cb8 ^ ((row & 7) << 4);                                 \
            const short* src = Abase + (size_t)row * K + (kt) * 64 + (scb >> 1); \
            short* dst = lbase + (r * 512 + wv * 64) * 8;                     \
            __builtin_amdgcn_global_load_lds((const AS1 void*)src,            \
                                             (AS3 void*)dst, 16, 0, 0);       \
        }                                                                     \
        _Pragma("unroll")                                                     \
        for (int r = 0; r < 4; ++r) {                                         \
            int c = r * 512 + tid;                                            \
            int row = c >> 3, cb8 = (c & 7) << 4;                             \
            int scb = cb8 ^ ((row & 7) << 4);                                 \
            const short* src = Bbase + (size_t)row * K + (kt) * 64 + (scb >> 1); \
            short* dst = lbase + 16384 + (r * 512 + wv * 64) * 8;             \
            __builtin_amdgcn_global_load_lds((const AS1 void*)src,            \
                                             (AS3 void*)dst, 16, 0, 0);       \
        }                                                                     \
    }

    STAGE(0, 0);

    for (int kt = 0; kt < NT; ++kt) {
        const int b = kt & 1;
        if (kt + 1 < NT) STAGE(kt + 1, b ^ 1);       // 8 loads stay in flight
        if (kt + 1 < NT) { WAITV(8); } else { WAITV(0); }
        BARRIER();   // buf b ready; all waves done reading b^1
        {
            const short* la = &lds[b * 32768];
            const short* lb = la + 16384;
#pragma unroll
            for (int ks = 0; ks < 2; ++ks) {
                short8 bv[4];
#pragma unroll
                for (int ni = 0; ni < 4; ++ni) {
                    int row = wn * 64 + ni * 16 + lr;
                    int col = (ks * 32 + kg * 8) ^ ((row & 7) << 3);
                    bv[ni] = *(const short8*)&lb[row * 64 + col];
                }
#pragma unroll
                for (int mh = 0; mh < 2; ++mh) {
                    short8 av[4];
#pragma unroll
                    for (int q = 0; q < 4; ++q) {
                        int row = wm * 128 + (mh * 4 + q) * 16 + lr;
                        int col = (ks * 32 + kg * 8) ^ ((row & 7) << 3);
                        av[q] = *(const short8*)&la[row * 64 + col];
                    }
                    __builtin_amdgcn_s_setprio(1);
#pragma unroll
                    for (int q = 0; q < 4; ++q)
#pragma unroll
                        for (int ni = 0; ni < 4; ++ni)
                            acc[mh * 4 + q][ni] = __builtin_amdgcn_mfma_f32_16x16x32_bf16(
                                av[q], bv[ni], acc[mh * 4 + q][ni], 0, 0, 0);
                    __builtin_amdgcn_s_setprio(0);
                }
            }
        }
        BARRIER();   // all waves done with buf b before next iter re-stages it
    }
#undef STAGE

#pragma unroll
    for (int mi = 0; mi < 8; ++mi) {
        int crow0 = m0 + wm * 128 + mi * 16 + kg * 4;
#pragma unroll
        for (int ni = 0; ni < 4; ++ni) {
            int ccol = n0 + wn * 64 + ni * 16 + lr;
#pragma unroll
            for (int i = 0; i < 4; ++i) {
                float v = acc[mi][ni][i];
                size_t crow = (size_t)(crow0 + i);
                if constexpr (EPI == G_SPLIT) {   // split-K partial: h | gate
                    if (ccol < 4096) atomicAdd(&C0[crow * 4096 + ccol], v);
                    else atomicAdd(&C1[crow * 4096 + (ccol - 4096)], v);
                } else {                          // split-K partial: plain
                    atomicAdd(&C0[crow * N + ccol], v);
                }
            }
        }
    }
}

// ---------------- 2-phase bf16 MFMA GEMM (GEMM2/3) ----------------
enum { EPI_PLAIN = 0, EPI_SPLIT = 1, EPI_ATOMIC = 2, EPI_SOFTPLUS = 3 };

template <int BM, int EPI>
__global__ __launch_bounds__(256)
void gemm_bt(const short* __restrict__ A, const short* __restrict__ B,
             float* __restrict__ C, float* __restrict__ C2,
             const float* __restrict__ bias,
             int M, int N, int K, int ldc, int kcLen) {
    __shared__ short A_lds[BM * 32];
    __shared__ short B_lds[128 * 32];
    const int tid = threadIdx.x;
    const int wv = tid >> 6, ln = tid & 63;
    const int lr = ln & 15, kg = ln >> 4;
    const int m0 = blockIdx.y * BM;
    const int n0 = blockIdx.x * 128;
    const int kbeg = blockIdx.z * kcLen;
    const int kend = kbeg + kcLen;
    const int wm = wv >> 1, wn = wv & 1;
    constexpr int MR = BM / 32;

    f32x4 acc[MR][4];
#pragma unroll
    for (int mi = 0; mi < MR; ++mi)
#pragma unroll
        for (int ni = 0; ni < 4; ++ni) acc[mi][ni] = (f32x4){0.f, 0.f, 0.f, 0.f};

    const int arow = tid >> 2;
    const int kq8 = (tid & 3) * 8;

    for (int k0 = kbeg; k0 < kend; k0 += 32) {
#pragma unroll
        for (int r = 0; r < BM / 64; ++r) {
            const short* srcA = A + (size_t)(m0 + r * 64 + arow) * K + (k0 + kq8);
            short* dstA = &A_lds[(r * 64 + wv * 16) * 32];
            __builtin_amdgcn_global_load_lds((const AS1 void*)srcA, (AS3 void*)dstA, 16, 0, 0);
        }
#pragma unroll
        for (int r = 0; r < 2; ++r) {
            int brow = n0 + r * 64 + arow;
            if (brow > N - 1) brow = N - 1;
            const short* srcB = B + (size_t)brow * K + (k0 + kq8);
            short* dstB = &B_lds[(r * 64 + wv * 16) * 32];
            __builtin_amdgcn_global_load_lds((const AS1 void*)srcB, (AS3 void*)dstB, 16, 0, 0);
        }
        __syncthreads();

        short8 av[MR], bv[4];
#pragma unroll
        for (int mi = 0; mi < MR; ++mi)
            av[mi] = *(const short8*)&A_lds[(wm * (BM / 2) + mi * 16 + lr) * 32 + kg * 8];
#pragma unroll
        for (int ni = 0; ni < 4; ++ni)
            bv[ni] = *(const short8*)&B_lds[(wn * 64 + ni * 16 + lr) * 32 + kg * 8];
#pragma unroll
        for (int mi = 0; mi < MR; ++mi)
#pragma unroll
            for (int ni = 0; ni < 4; ++ni)
                acc[mi][ni] = __builtin_amdgcn_mfma_f32_16x16x32_bf16(av[mi], bv[ni], acc[mi][ni], 0, 0, 0);
        __syncthreads();
    }

#pragma unroll
    for (int mi = 0; mi < MR; ++mi) {
        int crow0 = m0 + wm * (BM / 2) + mi * 16 + kg * 4;
#pragma unroll
        for (int ni = 0; ni < 4; ++ni) {
            int ccol = n0 + wn * 64 + ni * 16 + lr;
#pragma unroll
            for (int i = 0; i < 4; ++i) {
                float v = acc[mi][ni][i];
                size_t crow = (size_t)(crow0 + i);
                if constexpr (EPI == EPI_PLAIN) {
                    C[crow * ldc + ccol] = v;
                } else if constexpr (EPI == EPI_SPLIT) {
                    if (ccol < 4096) C[crow * 4096 + ccol] = v;
                    else C2[crow * 4096 + (ccol - 4096)] = v;
                } else if constexpr (EPI == EPI_ATOMIC) {
                    if (ccol < N) atomicAdd(&C[crow * ldc + ccol], v);
                } else {
                    float x = v + bias[ccol];
                    C[crow * ldc + ccol] = fmaxf(x, 0.f) + log1pf(__expf(-fabsf(x)));
                }
            }
        }
    }
}

// ================= chunked selective scan =================
#define CLEN 16
#define NCH 64

__global__ __launch_bounds__(256)
void scan_p1(const float* __restrict__ dt, const float* __restrict__ hc,
             const float* __restrict__ ssmp, const float* __restrict__ A_log,
             float* __restrict__ Sbuf, float* __restrict__ dtsum) {
    const int tid = threadIdx.x;
    const int c = blockIdx.x & (NCH - 1);
    const int db = blockIdx.x >> 6;
    const int d = db * 256 + tid;
    const int t0 = c * CLEN;

    float Ac[16];
#pragma unroll
    for (int i = 0; i < 4; ++i) {
        float4 v = *(const float4*)&A_log[d * 16 + i * 4];
        Ac[i*4+0] = -__expf(v.x); Ac[i*4+1] = -__expf(v.y);
        Ac[i*4+2] = -__expf(v.z); Ac[i*4+3] = -__expf(v.w);
    }

    __shared__ float sB[CLEN][16];
    sB[tid >> 4][tid & 15] = ssmp[(t0 + (tid >> 4)) * 160 + 128 + (tid & 15)];
    __syncthreads();

    float st[16];
#pragma unroll
    for (int n = 0; n < 16; ++n) st[n] = 0.f;
    float ds = 0.f;

    for (int tt = 0; tt < CLEN; ++tt) {
        float dtv = dt[(size_t)(t0 + tt) * 4096 + d];
        float hcv = hc[(size_t)(t0 + tt) * 4096 + d];
        float du = dtv * hcv;
        ds += dtv;
#pragma unroll
        for (int n = 0; n < 16; ++n) {
            float dA = __expf(dtv * Ac[n]);
            st[n] = fmaf(dA, st[n], du * sB[tt][n]);
        }
    }

    float* o = Sbuf + ((size_t)c * 4096 + d) * 16;
#pragma unroll
    for (int i = 0; i < 4; ++i)
        *(float4*)&o[i * 4] = make_float4(st[i*4], st[i*4+1], st[i*4+2], st[i*4+3]);
    dtsum[c * 4096 + d] = ds;
}

// batch-load combine: all 64 chunk-states into registers (static indexing),
// then a register-only fma chain — kills the 64 serial HBM round-trips.
__global__ __launch_bounds__(256)
void scan_p2(const float* __restrict__ A_log, const float* __restrict__ dtsum,
             float* __restrict__ S) {
    const int idx = blockIdx.x * 256 + threadIdx.x;   // (d,n), 65536
    const int d = idx >> 4;
    const float Ac = -__expf(A_log[idx]);

    float sl[NCH], Pv[NCH];
#pragma unroll
    for (int c = 0; c < NCH; ++c) sl[c] = S[(size_t)c * 65536 + idx];
#pragma unroll
    for (int c = 0; c < NCH; ++c) Pv[c] = __expf(Ac * dtsum[c * 4096 + d]);

    float s = 0.f;
#pragma unroll
    for (int c = 0; c < NCH; ++c) {
        S[(size_t)c * 65536 + idx] = s;   // initial state for chunk c
        s = fmaf(Pv[c], s, sl[c]);
    }
}

__global__ __launch_bounds__(256)
void scan_p3(const float* __restrict__ dt, const float* __restrict__ hc,
             const float* __restrict__ ssmp, const float* __restrict__ A_log,
             const float* __restrict__ Dp, const float* __restrict__ gate,
             const float* __restrict__ Sinit, unsigned short* __restrict__ y_bf) {
    const int tid = threadIdx.x;
    const int c = blockIdx.x & (NCH - 1);
    const int db = blockIdx.x >> 6;
    const int d = db * 256 + tid;
    const int t0 = c * CLEN;

    float Ac[16];
#pragma unroll
    for (int i = 0; i < 4; ++i) {
        float4 v = *(const float4*)&A_log[d * 16 + i * 4];
        Ac[i*4+0] = -__expf(v.x); Ac[i*4+1] = -__expf(v.y);
        Ac[i*4+2] = -__expf(v.z); Ac[i*4+3] = -__expf(v.w);
    }
    const float Dcoef = Dp[d];

    __shared__ float sB[CLEN][16], sC[CLEN][16];
    {
        int tt = tid >> 4, nn = tid & 15;
        sB[tt][nn] = ssmp[(t0 + tt) * 160 + 128 + nn];
        sC[tt][nn] = ssmp[(t0 + tt) * 160 + 144 + nn];
    }
    __syncthreads();

    float st[16];
    {
        const float* si = Sinit + ((size_t)c * 4096 + d) * 16;
#pragma unroll
        for (int i = 0; i < 4; ++i) {
            float4 v = *(const float4*)&si[i * 4];
            st[i*4] = v.x; st[i*4+1] = v.y; st[i*4+2] = v.z; st[i*4+3] = v.w;
        }
    }

    for (int tt = 0; tt < CLEN; ++tt) {
        size_t g = (size_t)(t0 + tt) * 4096 + d;
        float dtv = dt[g];
        float hcv = hc[g];
        float du = dtv * hcv;
        float p[16];
#pragma unroll
        for (int n = 0; n < 16; ++n) {
            float dA = __expf(dtv * Ac[n]);
            st[n] = fmaf(dA, st[n], du * sB[tt][n]);
            p[n] = st[n] * sC[tt][n];
        }
#pragma unroll
        for (int n = 0; n < 8; ++n) p[n] += p[n + 8];
#pragma unroll
        for (int n = 0; n < 4; ++n) p[n] += p[n + 4];
        p[0] += p[2]; p[1] += p[3];
        float csum = p[0] + p[1];
        float gv = gate[g];
        float yv = (csum + hcv * Dcoef) * (gv / (1.f + __expf(-gv)));
        y_bf[g] = f2bf(yv);
    }
}

// ---------------- launch ----------------
extern "C" void kernel_launch(void* const* d_in, const int* in_sizes, int n_in,
                              void* d_out, int out_size, void* d_ws, size_t ws_size,
                              hipStream_t stream) {
    (void)in_sizes; (void)n_in; (void)out_size; (void)ws_size;
    const float* hidden = (const float*)d_in[0];
    const float* W_in   = (const float*)d_in[1];
    const float* conv_w = (const float*)d_in[2];
    const float* conv_b = (const float*)d_in[3];
    const float* W_x    = (const float*)d_in[4];
    const float* W_dt   = (const float*)d_in[5];
    const float* b_dt   = (const float*)d_in[6];
    const float* A_log  = (const float*)d_in[7];
    const float* D_p    = (const float*)d_in[8];
    const float* W_out  = (const float*)d_in[9];
    float* out = (float*)d_out;

    char* w = (char*)d_ws;
    unsigned short* hid_bf = (unsigned short*)w;  w += (size_t)1024 * 2048 * 2;
    unsigned short* Wbig   = (unsigned short*)w;  w += (size_t)8192 * 2048 * 2;
    float* h_buf           = (float*)w;           w += (size_t)1024 * 4096 * 4;
    float* gate            = (float*)w;           w += (size_t)1024 * 4096 * 4;
    float* hc_f            = (float*)w;           w += (size_t)1024 * 4096 * 4;
    unsigned short* hc_bf  = (unsigned short*)w;  w += (size_t)1024 * 4096 * 2;
    float* ssmp            = (float*)w;           w += (size_t)1024 * 160 * 4;
    unsigned short* ts_bf  = (unsigned short*)w;  w += (size_t)1024 * 128 * 2;
    unsigned short* Wx_bf  = (unsigned short*)w;  w += (size_t)160 * 4096 * 2;
    unsigned short* Wdt_bf = (unsigned short*)w;  w += (size_t)4096 * 128 * 2;
    unsigned short* y_bf   = (unsigned short*)w;  w += (size_t)1024 * 4096 * 2;
    float* Sbuf            = (float*)w;           w += (size_t)NCH * 4096 * 16 * 4;
    float* dtsum           = (float*)w;           w += (size_t)NCH * 4096 * 4;

    // zero split-K atomic targets
    hipMemsetAsync(ssmp, 0, (size_t)1024 * 160 * 4, stream);
    hipMemsetAsync(out, 0, (size_t)1024 * 2048 * 4, stream);
    hipMemsetAsync(h_buf, 0, (size_t)1024 * 4096 * 4, stream);
    hipMemsetAsync(gate, 0, (size_t)1024 * 4096 * 4, stream);

    cvt_f32_bf16<<<2048, 256, 0, stream>>>(hidden, hid_bf, 1024 * 2048 / 4);
    cvt_f32_bf16<<<4096, 256, 0, stream>>>(W_in, Wbig, 8192 * 2048 / 4);
    cvt_f32_bf16<<<640, 256, 0, stream>>>(W_x, Wx_bf, 160 * 4096 / 4);
    cvt_f32_bf16<<<512, 256, 0, stream>>>(W_dt, Wdt_bf, 4096 * 128 / 4);

    // GEMM1: proj = hidden @ W_in^T -> split h | gate (256x256, split-K x2)
    gemm256<G_SPLIT><<<dim3(128, 1, 2), 512, 0, stream>>>(
        (const short*)hid_bf, (const short*)Wbig, h_buf, gate, 8192, 2048, 1024);

    conv_silu<<<16384, 256, 0, stream>>>(h_buf, conv_w, conv_b, hc_f, hc_bf);

    cvt_f32_bf16<<<2048, 256, 0, stream>>>(W_out, Wbig, 2048 * 4096 / 4);

    gemm_bt<128, EPI_ATOMIC><<<dim3(2, 8, 16), 256, 0, stream>>>(
        (const short*)hc_bf, (const short*)Wx_bf, ssmp, nullptr, nullptr,
        1024, 160, 4096, 160, 256);

    cvt_ts<<<128, 256, 0, stream>>>(ssmp, ts_bf);

    gemm_bt<128, EPI_SOFTPLUS><<<dim3(32, 8, 1), 256, 0, stream>>>(
        (const short*)ts_bf, (const short*)Wdt_bf, h_buf, nullptr, b_dt,
        1024, 4096, 128, 4096, 128);

    scan_p1<<<NCH * 16, 256, 0, stream>>>(h_buf, hc_f, ssmp, A_log, Sbuf, dtsum);
    scan_p2<<<256, 256, 0, stream>>>(A_log, dtsum, Sbuf);
    scan_p3<<<NCH * 16, 256, 0, stream>>>(h_buf, hc_f, ssmp, A_log, D_p, gate, Sbuf, y_bf);

    // GEMM4: out = y @ W_out^T (256x256, split-K x8)
    gemm256<G_ATOMIC><<<dim3(32, 1, 8), 512, 0, stream>>>(
        (const short*)y_bf, (const short*)Wbig, out, nullptr, 2048, 4096, 512);
}

// Round 6
// 220.401 us; speedup vs baseline: 1.4532x; 1.4532x over previous
//
#include <hip/hip_runtime.h>
#include <math.h>

#define AS1 __attribute__((address_space(1)))
#define AS3 __attribute__((address_space(3)))

typedef __attribute__((ext_vector_type(8))) short short8;
typedef __attribute__((ext_vector_type(4))) float f32x4;

#define WAITV(n) asm volatile("s_waitcnt vmcnt(" #n ")" ::: "memory")
#define BARRIER() asm volatile("s_barrier" ::: "memory")

static __device__ __forceinline__ unsigned short f2bf(float f) {
    unsigned u = __float_as_uint(f);
    unsigned r = (u + 0x7fffu + ((u >> 16) & 1u)) >> 16;
    return (unsigned short)r;
}

// ---------------- f32 -> bf16 convert (vectorized x4) ----------------
__global__ __launch_bounds__(256) void cvt_f32_bf16(const float* __restrict__ src,
                                                    unsigned short* __restrict__ dst,
                                                    int n4) {
    int i = blockIdx.x * 256 + threadIdx.x;
    int stride = gridDim.x * 256;
    for (; i < n4; i += stride) {
        float4 v = ((const float4*)src)[i];
        ushort4 o;
        o.x = f2bf(v.x); o.y = f2bf(v.y); o.z = f2bf(v.z); o.w = f2bf(v.w);
        ((ushort4*)dst)[i] = o;
    }
}

// extract ts (cols 0..127 of ssm_p, row stride 160) -> dense bf16 1024x128
__global__ __launch_bounds__(256) void cvt_ts(const float* __restrict__ ssmp,
                                              unsigned short* __restrict__ ts) {
    int i = blockIdx.x * 256 + threadIdx.x;   // < 32768
    int t = i >> 5, c4 = (i & 31) * 4;
    float4 v = *(const float4*)&ssmp[t * 160 + c4];
    ushort4 o;
    o.x = f2bf(v.x); o.y = f2bf(v.y); o.z = f2bf(v.z); o.w = f2bf(v.w);
    *(ushort4*)&ts[t * 128 + c4] = o;
}

// ---------------- depthwise causal conv (K=4) + bias + silu ----------------
__global__ __launch_bounds__(256) void conv_silu(const float* __restrict__ h,
                                                 const float* __restrict__ cw,
                                                 const float* __restrict__ cb,
                                                 float* __restrict__ hc_f,
                                                 unsigned short* __restrict__ hc_bf) {
    int idx = blockIdx.x * 256 + threadIdx.x;   // < 1024*4096
    int d = idx & 4095, t = idx >> 12;
    float acc = cb[d];
    float4 w = *(const float4*)&cw[d * 4];
    const float* wp = (const float*)&w;
#pragma unroll
    for (int k = 0; k < 4; ++k) {
        int tt = t + k - 3;
        if (tt >= 0) acc += h[tt * 4096 + d] * wp[k];
    }
    float s = acc / (1.f + __expf(-acc));   // silu
    hc_f[idx] = s;
    hc_bf[idx] = f2bf(s);
}

// ---------------- reduce 4 split-K partials -> out ----------------
__global__ __launch_bounds__(256) void reduce4(const float* __restrict__ pA,
                                               const float* __restrict__ pB,
                                               float* __restrict__ out, int n4) {
    int i = blockIdx.x * 256 + threadIdx.x;
    int stride = gridDim.x * 256;
    const size_t MN4 = (size_t)1024 * 2048 / 4;
    for (; i < n4; i += stride) {
        float4 a = ((const float4*)pA)[i];
        float4 b = ((const float4*)pA)[i + MN4];
        float4 c = ((const float4*)pB)[i];
        float4 d = ((const float4*)pB)[i + MN4];
        float4 o;
        o.x = (a.x + b.x) + (c.x + d.x);
        o.y = (a.y + b.y) + (c.y + d.y);
        o.z = (a.z + b.z) + (c.z + d.z);
        o.w = (a.w + b.w) + (c.w + d.w);
        ((float4*)out)[i] = o;
    }
}

// ======== pipelined bf16 MFMA GEMM: C(M,N) = A(M,K) @ B(N,K)^T ========
// BM=128, BN=256, BK=64. 512 threads = 8 waves (2M x 4N). THREE LDS buffers
// (144KB), prefetch depth 2: tiles kt+1 and kt+2 stay in flight across tile
// kt's compute (counted vmcnt(12)/(6) — never 0 in steady state). Raw
// s_barrier, XOR-swizzled LDS via pre-swizzled global source (linear dest
// for global_load_lds, rule 21), setprio around MFMA, XCD-bijective swizzle.
// M fixed = 1024 (8 tile rows of 128).
enum { P_SPLIT = 0, P_PART = 1 };

template <int EPI>
__global__ __launch_bounds__(512, 2)
void gemm8p(const short* __restrict__ A, const short* __restrict__ B,
            float* __restrict__ C0, float* __restrict__ C1,
            int N, int K, int kchunk) {
    __shared__ short lds[3 * 24576];   // per buf: A 128x64 (8192) + B 256x64 (16384)

    const int tid = threadIdx.x;
    const int wv = tid >> 6, ln = tid & 63;
    const int lr = ln & 15, kg = ln >> 4;
    const int wm = wv >> 2, wn = wv & 3;

    const int nwg = gridDim.x;
    const int bid = blockIdx.x;
    const int swz = (bid & 7) * (nwg >> 3) + (bid >> 3);   // nwg % 8 == 0
    const int by = swz & 7, bx = swz >> 3;
    const int m0 = by * 128;
    const int n0 = bx * 256;
    const int kbeg = blockIdx.z * kchunk;
    const int NT = kchunk >> 6;

    f32x4 acc[4][4];
#pragma unroll
    for (int mi = 0; mi < 4; ++mi)
#pragma unroll
        for (int ni = 0; ni < 4; ++ni) acc[mi][ni] = (f32x4){0.f, 0.f, 0.f, 0.f};

    const short* Abase = A + (size_t)m0 * K + kbeg;
    const short* Bbase = B + (size_t)n0 * K + kbeg;

    // Stage K-tile kt into buffer b (6 global_load_lds per thread).
    // LDS dest linear; source column pre-swizzled so that after the write,
    // LDS[row][col ^ ((row&7)<<3)] = Global[row][col]   (rule 21).
#define STAGE(kt, b)                                                          \
    {                                                                         \
        short* lbase = &lds[(b) * 24576];                                     \
        _Pragma("unroll")                                                     \
        for (int r = 0; r < 2; ++r) {                                         \
            int c = r * 512 + tid;                                            \
            int row = c >> 3, cb8 = (c & 7) << 4;                             \
            int scb = cb8 ^ ((row & 7) << 4);                                 \
            const short* src = Abase + (size_t)row * K + (kt) * 64 + (scb >> 1); \
            short* dst = lbase + (r * 512 + wv * 64) * 8;                     \
            __builtin_amdgcn_global_load_lds((const AS1 void*)src,            \
                                             (AS3 void*)dst, 16, 0, 0);       \
        }                                                                     \
        _Pragma("unroll")                                                     \
        for (int r = 0; r < 4; ++r) {                                         \
            int c = r * 512 + tid;                                            \
            int row = c >> 3, cb8 = (c & 7) << 4;                             \
            int scb = cb8 ^ ((row & 7) << 4);                                 \
            const short* src = Bbase + (size_t)row * K + (kt) * 64 + (scb >> 1); \
            short* dst = lbase + 8192 + (r * 512 + wv * 64) * 8;              \
            __builtin_amdgcn_global_load_lds((const AS1 void*)src,            \
                                             (AS3 void*)dst, 16, 0, 0);       \
        }                                                                     \
    }

    STAGE(0, 0);
    if (NT > 1) STAGE(1, 1);

    for (int kt = 0; kt < NT; ++kt) {
        const int b = kt % 3;
        // keep pipeline 2 deep: stage kt+2 into the buffer freed at iter kt-1
        if (kt + 2 < NT) STAGE(kt + 2, (kt + 2) % 3);
        // wait until tile kt's 6 loads are complete; leave deeper tiles in flight
        int ahead = NT - 1 - kt;
        if (ahead > 2) ahead = 2;
        if (ahead == 2) { WAITV(12); } else if (ahead == 1) { WAITV(6); } else { WAITV(0); }
        BARRIER();   // buf b ready for all waves
        {
            const short* la = &lds[b * 24576];
            const short* lb = la + 8192;
#pragma unroll
            for (int ks = 0; ks < 2; ++ks) {
                short8 av[4], bv[4];
#pragma unroll
                for (int mi = 0; mi < 4; ++mi) {
                    int row = wm * 64 + mi * 16 + lr;
                    int col = (ks * 32 + kg * 8) ^ ((row & 7) << 3);
                    av[mi] = *(const short8*)&la[row * 64 + col];
                }
#pragma unroll
                for (int ni = 0; ni < 4; ++ni) {
                    int row = wn * 64 + ni * 16 + lr;
                    int col = (ks * 32 + kg * 8) ^ ((row & 7) << 3);
                    bv[ni] = *(const short8*)&lb[row * 64 + col];
                }
                __builtin_amdgcn_s_setprio(1);
#pragma unroll
                for (int mi = 0; mi < 4; ++mi)
#pragma unroll
                    for (int ni = 0; ni < 4; ++ni)
                        acc[mi][ni] = __builtin_amdgcn_mfma_f32_16x16x32_bf16(
                            av[mi], bv[ni], acc[mi][ni], 0, 0, 0);
                __builtin_amdgcn_s_setprio(0);
            }
        }
        BARRIER();   // all waves done reading buf b; it may be re-staged at kt+1
    }
#undef STAGE

#pragma unroll
    for (int mi = 0; mi < 4; ++mi) {
        int crow0 = m0 + wm * 64 + mi * 16 + kg * 4;
#pragma unroll
        for (int ni = 0; ni < 4; ++ni) {
            int ccol = n0 + wn * 64 + ni * 16 + lr;
#pragma unroll
            for (int i = 0; i < 4; ++i) {
                float v = acc[mi][ni][i];
                size_t crow = (size_t)(crow0 + i);
                if constexpr (EPI == P_SPLIT) {       // h | gate
                    if (ccol < 4096) C0[crow * 4096 + ccol] = v;
                    else C1[crow * 4096 + (ccol - 4096)] = v;
                } else {                              // split-K partial stores
                    // z = 0,1 -> C0 region; z = 2,3 -> C1 region
                    float* Cz = (blockIdx.z < 2 ? C0 : C1) +
                                (size_t)(blockIdx.z & 1) * 1024 * 2048;
                    Cz[crow * N + ccol] = v;
                }
            }
        }
    }
}

// ---------------- 2-phase bf16 MFMA GEMM (GEMM2/3) ----------------
enum { EPI_PLAIN = 0, EPI_SPLIT = 1, EPI_ATOMIC = 2, EPI_SOFTPLUS = 3 };

template <int BM, int EPI>
__global__ __launch_bounds__(256)
void gemm_bt(const short* __restrict__ A, const short* __restrict__ B,
             float* __restrict__ C, float* __restrict__ C2,
             const float* __restrict__ bias,
             int M, int N, int K, int ldc, int kcLen) {
    __shared__ short A_lds[BM * 32];
    __shared__ short B_lds[128 * 32];
    const int tid = threadIdx.x;
    const int wv = tid >> 6, ln = tid & 63;
    const int lr = ln & 15, kg = ln >> 4;
    const int m0 = blockIdx.y * BM;
    const int n0 = blockIdx.x * 128;
    const int kbeg = blockIdx.z * kcLen;
    const int kend = kbeg + kcLen;
    const int wm = wv >> 1, wn = wv & 1;
    constexpr int MR = BM / 32;

    f32x4 acc[MR][4];
#pragma unroll
    for (int mi = 0; mi < MR; ++mi)
#pragma unroll
        for (int ni = 0; ni < 4; ++ni) acc[mi][ni] = (f32x4){0.f, 0.f, 0.f, 0.f};

    const int arow = tid >> 2;
    const int kq8 = (tid & 3) * 8;

    for (int k0 = kbeg; k0 < kend; k0 += 32) {
#pragma unroll
        for (int r = 0; r < BM / 64; ++r) {
            const short* srcA = A + (size_t)(m0 + r * 64 + arow) * K + (k0 + kq8);
            short* dstA = &A_lds[(r * 64 + wv * 16) * 32];
            __builtin_amdgcn_global_load_lds((const AS1 void*)srcA, (AS3 void*)dstA, 16, 0, 0);
        }
#pragma unroll
        for (int r = 0; r < 2; ++r) {
            int brow = n0 + r * 64 + arow;
            if (brow > N - 1) brow = N - 1;
            const short* srcB = B + (size_t)brow * K + (k0 + kq8);
            short* dstB = &B_lds[(r * 64 + wv * 16) * 32];
            __builtin_amdgcn_global_load_lds((const AS1 void*)srcB, (AS3 void*)dstB, 16, 0, 0);
        }
        __syncthreads();

        short8 av[MR], bv[4];
#pragma unroll
        for (int mi = 0; mi < MR; ++mi)
            av[mi] = *(const short8*)&A_lds[(wm * (BM / 2) + mi * 16 + lr) * 32 + kg * 8];
#pragma unroll
        for (int ni = 0; ni < 4; ++ni)
            bv[ni] = *(const short8*)&B_lds[(wn * 64 + ni * 16 + lr) * 32 + kg * 8];
#pragma unroll
        for (int mi = 0; mi < MR; ++mi)
#pragma unroll
            for (int ni = 0; ni < 4; ++ni)
                acc[mi][ni] = __builtin_amdgcn_mfma_f32_16x16x32_bf16(av[mi], bv[ni], acc[mi][ni], 0, 0, 0);
        __syncthreads();
    }

#pragma unroll
    for (int mi = 0; mi < MR; ++mi) {
        int crow0 = m0 + wm * (BM / 2) + mi * 16 + kg * 4;
#pragma unroll
        for (int ni = 0; ni < 4; ++ni) {
            int ccol = n0 + wn * 64 + ni * 16 + lr;
#pragma unroll
            for (int i = 0; i < 4; ++i) {
                float v = acc[mi][ni][i];
                size_t crow = (size_t)(crow0 + i);
                if constexpr (EPI == EPI_PLAIN) {
                    C[crow * ldc + ccol] = v;
                } else if constexpr (EPI == EPI_SPLIT) {
                    if (ccol < 4096) C[crow * 4096 + ccol] = v;
                    else C2[crow * 4096 + (ccol - 4096)] = v;
                } else if constexpr (EPI == EPI_ATOMIC) {
                    if (ccol < N) atomicAdd(&C[crow * ldc + ccol], v);
                } else {
                    float x = v + bias[ccol];
                    C[crow * ldc + ccol] = fmaxf(x, 0.f) + log1pf(__expf(-fabsf(x)));
                }
            }
        }
    }
}

// ================= chunked selective scan =================
#define CLEN 16
#define NCH 64

__global__ __launch_bounds__(256)
void scan_p1(const float* __restrict__ dt, const float* __restrict__ hc,
             const float* __restrict__ ssmp, const float* __restrict__ A_log,
             float* __restrict__ Sbuf, float* __restrict__ dtsum) {
    const int tid = threadIdx.x;
    const int c = blockIdx.x & (NCH - 1);
    const int db = blockIdx.x >> 6;
    const int d = db * 256 + tid;
    const int t0 = c * CLEN;

    float Ac[16];
#pragma unroll
    for (int i = 0; i < 4; ++i) {
        float4 v = *(const float4*)&A_log[d * 16 + i * 4];
        Ac[i*4+0] = -__expf(v.x); Ac[i*4+1] = -__expf(v.y);
        Ac[i*4+2] = -__expf(v.z); Ac[i*4+3] = -__expf(v.w);
    }

    __shared__ float sB[CLEN][16];
    sB[tid >> 4][tid & 15] = ssmp[(t0 + (tid >> 4)) * 160 + 128 + (tid & 15)];
    __syncthreads();

    float st[16];
#pragma unroll
    for (int n = 0; n < 16; ++n) st[n] = 0.f;
    float ds = 0.f;

    for (int tt = 0; tt < CLEN; ++tt) {
        float dtv = dt[(size_t)(t0 + tt) * 4096 + d];
        float hcv = hc[(size_t)(t0 + tt) * 4096 + d];
        float du = dtv * hcv;
        ds += dtv;
#pragma unroll
        for (int n = 0; n < 16; ++n) {
            float dA = __expf(dtv * Ac[n]);
            st[n] = fmaf(dA, st[n], du * sB[tt][n]);
        }
    }

    float* o = Sbuf + ((size_t)c * 4096 + d) * 16;
#pragma unroll
    for (int i = 0; i < 4; ++i)
        *(float4*)&o[i * 4] = make_float4(st[i*4], st[i*4+1], st[i*4+2], st[i*4+3]);
    dtsum[c * 4096 + d] = ds;
}

// batch-load combine: all 64 chunk-states into registers (static indexing),
// then a register-only fma chain.
__global__ __launch_bounds__(256)
void scan_p2(const float* __restrict__ A_log, const float* __restrict__ dtsum,
             float* __restrict__ S) {
    const int idx = blockIdx.x * 256 + threadIdx.x;   // (d,n), 65536
    const int d = idx >> 4;
    const float Ac = -__expf(A_log[idx]);

    float sl[NCH], Pv[NCH];
#pragma unroll
    for (int c = 0; c < NCH; ++c) sl[c] = S[(size_t)c * 65536 + idx];
#pragma unroll
    for (int c = 0; c < NCH; ++c) Pv[c] = __expf(Ac * dtsum[c * 4096 + d]);

    float s = 0.f;
#pragma unroll
    for (int c = 0; c < NCH; ++c) {
        S[(size_t)c * 65536 + idx] = s;   // initial state for chunk c
        s = fmaf(Pv[c], s, sl[c]);
    }
}

__global__ __launch_bounds__(256)
void scan_p3(const float* __restrict__ dt, const float* __restrict__ hc,
             const float* __restrict__ ssmp, const float* __restrict__ A_log,
             const float* __restrict__ Dp, const float* __restrict__ gate,
             const float* __restrict__ Sinit, unsigned short* __restrict__ y_bf) {
    const int tid = threadIdx.x;
    const int c = blockIdx.x & (NCH - 1);
    const int db = blockIdx.x >> 6;
    const int d = db * 256 + tid;
    const int t0 = c * CLEN;

    float Ac[16];
#pragma unroll
    for (int i = 0; i < 4; ++i) {
        float4 v = *(const float4*)&A_log[d * 16 + i * 4];
        Ac[i*4+0] = -__expf(v.x); Ac[i*4+1] = -__expf(v.y);
        Ac[i*4+2] = -__expf(v.z); Ac[i*4+3] = -__expf(v.w);
    }
    const float Dcoef = Dp[d];

    __shared__ float sB[CLEN][16], sC[CLEN][16];
    {
        int tt = tid >> 4, nn = tid & 15;
        sB[tt][nn] = ssmp[(t0 + tt) * 160 + 128 + nn];
        sC[tt][nn] = ssmp[(t0 + tt) * 160 + 144 + nn];
    }
    __syncthreads();

    float st[16];
    {
        const float* si = Sinit + ((size_t)c * 4096 + d) * 16;
#pragma unroll
        for (int i = 0; i < 4; ++i) {
            float4 v = *(const float4*)&si[i * 4];
            st[i*4] = v.x; st[i*4+1] = v.y; st[i*4+2] = v.z; st[i*4+3] = v.w;
        }
    }

    for (int tt = 0; tt < CLEN; ++tt) {
        size_t g = (size_t)(t0 + tt) * 4096 + d;
        float dtv = dt[g];
        float hcv = hc[g];
        float du = dtv * hcv;
        float p[16];
#pragma unroll
        for (int n = 0; n < 16; ++n) {
            float dA = __expf(dtv * Ac[n]);
            st[n] = fmaf(dA, st[n], du * sB[tt][n]);
            p[n] = st[n] * sC[tt][n];
        }
#pragma unroll
        for (int n = 0; n < 8; ++n) p[n] += p[n + 8];
#pragma unroll
        for (int n = 0; n < 4; ++n) p[n] += p[n + 4];
        p[0] += p[2]; p[1] += p[3];
        float csum = p[0] + p[1];
        float gv = gate[g];
        float yv = (csum + hcv * Dcoef) * (gv / (1.f + __expf(-gv)));
        y_bf[g] = f2bf(yv);
    }
}

// ---------------- launch ----------------
extern "C" void kernel_launch(void* const* d_in, const int* in_sizes, int n_in,
                              void* d_out, int out_size, void* d_ws, size_t ws_size,
                              hipStream_t stream) {
    (void)in_sizes; (void)n_in; (void)out_size; (void)ws_size;
    const float* hidden = (const float*)d_in[0];
    const float* W_in   = (const float*)d_in[1];
    const float* conv_w = (const float*)d_in[2];
    const float* conv_b = (const float*)d_in[3];
    const float* W_x    = (const float*)d_in[4];
    const float* W_dt   = (const float*)d_in[5];
    const float* b_dt   = (const float*)d_in[6];
    const float* A_log  = (const float*)d_in[7];
    const float* D_p    = (const float*)d_in[8];
    const float* W_out  = (const float*)d_in[9];
    float* out = (float*)d_out;

    char* w = (char*)d_ws;
    unsigned short* hid_bf = (unsigned short*)w;  w += (size_t)1024 * 2048 * 2;
    unsigned short* Wbig   = (unsigned short*)w;  w += (size_t)8192 * 2048 * 2;
    float* h_buf           = (float*)w;           w += (size_t)1024 * 4096 * 4;
    float* gate            = (float*)w;           w += (size_t)1024 * 4096 * 4;
    float* hc_f            = (float*)w;           w += (size_t)1024 * 4096 * 4;  // also GEMM4 partials 2,3
    unsigned short* hc_bf  = (unsigned short*)w;  w += (size_t)1024 * 4096 * 2;
    float* ssmp            = (float*)w;           w += (size_t)1024 * 160 * 4;
    unsigned short* ts_bf  = (unsigned short*)w;  w += (size_t)1024 * 128 * 2;
    unsigned short* Wx_bf  = (unsigned short*)w;  w += (size_t)160 * 4096 * 2;
    unsigned short* Wdt_bf = (unsigned short*)w;  w += (size_t)4096 * 128 * 2;
    unsigned short* y_bf   = (unsigned short*)w;  w += (size_t)1024 * 4096 * 2;
    float* Sbuf            = (float*)w;           w += (size_t)NCH * 4096 * 16 * 4;  // also GEMM4 partials 0,1
    float* dtsum           = (float*)w;           w += (size_t)NCH * 4096 * 4;

    hipMemsetAsync(ssmp, 0, (size_t)1024 * 160 * 4, stream);   // GEMM2 atomic target

    cvt_f32_bf16<<<2048, 256, 0, stream>>>(hidden, hid_bf, 1024 * 2048 / 4);
    cvt_f32_bf16<<<4096, 256, 0, stream>>>(W_in, Wbig, 8192 * 2048 / 4);
    cvt_f32_bf16<<<640, 256, 0, stream>>>(W_x, Wx_bf, 160 * 4096 / 4);
    cvt_f32_bf16<<<512, 256, 0, stream>>>(W_dt, Wdt_bf, 4096 * 128 / 4);

    // GEMM1: proj = hidden @ W_in^T -> split h | gate (depth-2 pipelined)
    gemm8p<P_SPLIT><<<dim3(256, 1, 1), 512, 0, stream>>>(
        (const short*)hid_bf, (const short*)Wbig, h_buf, gate, 8192, 2048, 2048);

    conv_silu<<<16384, 256, 0, stream>>>(h_buf, conv_w, conv_b, hc_f, hc_bf);

    cvt_f32_bf16<<<2048, 256, 0, stream>>>(W_out, Wbig, 2048 * 4096 / 4);

    gemm_bt<128, EPI_ATOMIC><<<dim3(2, 8, 16), 256, 0, stream>>>(
        (const short*)hc_bf, (const short*)Wx_bf, ssmp, nullptr, nullptr,
        1024, 160, 4096, 160, 256);

    cvt_ts<<<128, 256, 0, stream>>>(ssmp, ts_bf);

    gemm_bt<128, EPI_SOFTPLUS><<<dim3(32, 8, 1), 256, 0, stream>>>(
        (const short*)ts_bf, (const short*)Wdt_bf, h_buf, nullptr, b_dt,
        1024, 4096, 128, 4096, 128);

    scan_p1<<<NCH * 16, 256, 0, stream>>>(h_buf, hc_f, ssmp, A_log, Sbuf, dtsum);
    scan_p2<<<256, 256, 0, stream>>>(A_log, dtsum, Sbuf);
    scan_p3<<<NCH * 16, 256, 0, stream>>>(h_buf, hc_f, ssmp, A_log, D_p, gate, Sbuf, y_bf);

    // GEMM4: out = y @ W_out^T — depth-2 pipelined, split-K x4 with
    // plain-store partials into dead Sbuf (z=0,1) / hc_f (z=2,3), then reduce.
    gemm8p<P_PART><<<dim3(64, 1, 4), 512, 0, stream>>>(
        (const short*)y_bf, (const short*)Wbig, Sbuf, hc_f, 2048, 4096, 1024);
    reduce4<<<2048, 256, 0, stream>>>(Sbuf, hc_f, out, 1024 * 2048 / 4);
}

// Round 7
// 216.182 us; speedup vs baseline: 1.4816x; 1.0195x over previous
//
#include <hip/hip_runtime.h>
#include <math.h>

#define AS1 __attribute__((address_space(1)))
#define AS3 __attribute__((address_space(3)))

typedef __attribute__((ext_vector_type(8))) short short8;
typedef __attribute__((ext_vector_type(4))) float f32x4;

#define WAITV(n) asm volatile("s_waitcnt vmcnt(" #n ")" ::: "memory")
#define LGKM0()  asm volatile("s_waitcnt lgkmcnt(0)" ::: "memory")
#define BARRIER() asm volatile("s_barrier" ::: "memory")
#define SCHEDB() __builtin_amdgcn_sched_barrier(0)

static __device__ __forceinline__ unsigned short f2bf(float f) {
    unsigned u = __float_as_uint(f);
    unsigned r = (u + 0x7fffu + ((u >> 16) & 1u)) >> 16;
    return (unsigned short)r;
}
static __device__ __forceinline__ float bf2f(unsigned short u) {
    return __uint_as_float(((unsigned)u) << 16);
}

// ---------------- f32 -> bf16 convert (vectorized x4) ----------------
__global__ __launch_bounds__(256) void cvt_f32_bf16(const float* __restrict__ src,
                                                    unsigned short* __restrict__ dst,
                                                    int n4) {
    int i = blockIdx.x * 256 + threadIdx.x;
    int stride = gridDim.x * 256;
    for (; i < n4; i += stride) {
        float4 v = ((const float4*)src)[i];
        ushort4 o;
        o.x = f2bf(v.x); o.y = f2bf(v.y); o.z = f2bf(v.z); o.w = f2bf(v.w);
        ((ushort4*)dst)[i] = o;
    }
}

// extract ts (cols 0..127 of ssm_p, row stride 160) -> dense bf16 1024x128
__global__ __launch_bounds__(256) void cvt_ts(const float* __restrict__ ssmp,
                                              unsigned short* __restrict__ ts) {
    int i = blockIdx.x * 256 + threadIdx.x;   // < 32768
    int t = i >> 5, c4 = (i & 31) * 4;
    float4 v = *(const float4*)&ssmp[t * 160 + c4];
    ushort4 o;
    o.x = f2bf(v.x); o.y = f2bf(v.y); o.z = f2bf(v.z); o.w = f2bf(v.w);
    *(ushort4*)&ts[t * 128 + c4] = o;
}

// ------- depthwise causal conv (K=4) + bias + silu -> hc bf16 only -------
__global__ __launch_bounds__(256) void conv_silu(const float* __restrict__ h,
                                                 const float* __restrict__ cw,
                                                 const float* __restrict__ cb,
                                                 unsigned short* __restrict__ hc_bf) {
    int idx = blockIdx.x * 256 + threadIdx.x;   // < 1024*4096
    int d = idx & 4095, t = idx >> 12;
    float acc = cb[d];
    float4 w = *(const float4*)&cw[d * 4];
    const float* wp = (const float*)&w;
#pragma unroll
    for (int k = 0; k < 4; ++k) {
        int tt = t + k - 3;
        if (tt >= 0) acc += h[tt * 4096 + d] * wp[k];
    }
    float s = acc / (1.f + __expf(-acc));   // silu
    hc_bf[idx] = f2bf(s);
}

// ---------------- reduce 4 split-K partials -> out ----------------
__global__ __launch_bounds__(256) void reduce4(const float* __restrict__ pA,
                                               const float* __restrict__ pB,
                                               float* __restrict__ out, int n4) {
    int i = blockIdx.x * 256 + threadIdx.x;
    int stride = gridDim.x * 256;
    const size_t MN4 = (size_t)1024 * 2048 / 4;
    for (; i < n4; i += stride) {
        float4 a = ((const float4*)pA)[i];
        float4 b = ((const float4*)pA)[i + MN4];
        float4 c = ((const float4*)pB)[i];
        float4 d = ((const float4*)pB)[i + MN4];
        float4 o;
        o.x = (a.x + b.x) + (c.x + d.x);
        o.y = (a.y + b.y) + (c.y + d.y);
        o.z = (a.z + b.z) + (c.z + d.z);
        o.w = (a.w + b.w) + (c.w + d.w);
        ((float4*)out)[i] = o;
    }
}

// ======== phased pipelined bf16 MFMA GEMM: C(M,N)=A(M,K)@B(N,K)^T ========
// BM=128, BN=256, BK=64. 512 threads = 8 waves (2M x 4N), wave tile 64x64.
// m201-style schedule: per K-tile, 4 phases of {ds_read subtile + 2
// global_load_lds for tile kt+2 + lgkmcnt(0) + setprio + 8 MFMA + barrier}.
// Counted vmcnt(6) once per tile (never 0 in steady state). 3-buf LDS
// (144KB). XOR-swizzled LDS via pre-swizzled global source (linear dest,
// rule 21). XCD-bijective block swizzle. M fixed = 1024.
enum { P_GATE = 0, P_PART = 1 };

template <int EPI>
__global__ __launch_bounds__(512, 2)
void gemm8p(const short* __restrict__ A, const short* __restrict__ B,
            void* __restrict__ C0v, void* __restrict__ C1v,
            int N, int K, int kchunk) {
    __shared__ short lds[3 * 24576];   // per buf: A 128x64 (8192) + B 256x64 (16384)

    const int tid = threadIdx.x;
    const int wv = tid >> 6, ln = tid & 63;
    const int lr = ln & 15, kg = ln >> 4;
    const int wm = wv >> 2, wn = wv & 3;

    const int nwg = gridDim.x;
    const int bid = blockIdx.x;
    const int swz = (bid & 7) * (nwg >> 3) + (bid >> 3);   // nwg % 8 == 0
    const int by = swz & 7, bx = swz >> 3;
    const int m0 = by * 128;
    const int n0 = bx * 256;
    const int kbeg = blockIdx.z * kchunk;
    const int NT = kchunk >> 6;

    f32x4 acc[4][4];
#pragma unroll
    for (int mi = 0; mi < 4; ++mi)
#pragma unroll
        for (int ni = 0; ni < 4; ++ni) acc[mi][ni] = (f32x4){0.f, 0.f, 0.f, 0.f};

    const short* Abase = A + (size_t)m0 * K + kbeg;
    const short* Bbase = B + (size_t)n0 * K + kbeg;

// source column pre-swizzled so LDS[row][byte j] = Global[row][byte j ^ ((row&7)<<4)]
#define STAGE_A(kt, b)                                                        \
    {                                                                         \
        short* lbase = &lds[(b) * 24576];                                     \
        _Pragma("unroll")                                                     \
        for (int r = 0; r < 2; ++r) {                                         \
            int c = r * 512 + tid;                                            \
            int row = c >> 3, cb8 = (c & 7) << 4;                             \
            int scb = cb8 ^ ((row & 7) << 4);                                 \
            const short* src = Abase + (size_t)row * K + (kt) * 64 + (scb >> 1); \
            short* dst = lbase + (r * 512 + wv * 64) * 8;                     \
            __builtin_amdgcn_global_load_lds((const AS1 void*)src,            \
                                             (AS3 void*)dst, 16, 0, 0);       \
        }                                                                     \
    }
#define STAGE_B(kt, b, r0)                                                    \
    {                                                                         \
        short* lbase = &lds[(b) * 24576];                                     \
        _Pragma("unroll")                                                     \
        for (int r = (r0); r < (r0) + 2; ++r) {                               \
            int c = r * 512 + tid;                                            \
            int row = c >> 3, cb8 = (c & 7) << 4;                             \
            int scb = cb8 ^ ((row & 7) << 4);                                 \
            const short* src = Bbase + (size_t)row * K + (kt) * 64 + (scb >> 1); \
            short* dst = lbase + 8192 + (r * 512 + wv * 64) * 8;              \
            __builtin_amdgcn_global_load_lds((const AS1 void*)src,            \
                                             (AS3 void*)dst, 16, 0, 0);       \
        }                                                                     \
    }
#define RD_A(dst, mi, ks)                                                     \
    { int row = wm * 64 + (mi) * 16 + lr;                                     \
      int col = ((ks) * 32 + kg * 8) ^ ((row & 7) << 3);                      \
      dst = *(const short8*)&la[row * 64 + col]; }
#define RD_B(dst, ni, ks)                                                     \
    { int row = wn * 64 + (ni) * 16 + lr;                                     \
      int col = ((ks) * 32 + kg * 8) ^ ((row & 7) << 3);                      \
      dst = *(const short8*)&lb[row * 64 + col]; }
#define MFMA4(mi, a)                                                          \
    acc[mi][0] = __builtin_amdgcn_mfma_f32_16x16x32_bf16(a, vb0, acc[mi][0], 0, 0, 0); \
    acc[mi][1] = __builtin_amdgcn_mfma_f32_16x16x32_bf16(a, vb1, acc[mi][1], 0, 0, 0); \
    acc[mi][2] = __builtin_amdgcn_mfma_f32_16x16x32_bf16(a, vb2, acc[mi][2], 0, 0, 0); \
    acc[mi][3] = __builtin_amdgcn_mfma_f32_16x16x32_bf16(a, vb3, acc[mi][3], 0, 0, 0);

    // prologue: fully stage tiles 0 and 1
    STAGE_A(0, 0); STAGE_B(0, 0, 0); STAGE_B(0, 0, 2);
    if (NT > 1) { STAGE_A(1, 1); STAGE_B(1, 1, 0); STAGE_B(1, 1, 2); }

    for (int kt = 0; kt < NT; ++kt) {
        const int b = kt % 3;
        const int bnx = (kt + 2) % 3;
        const bool pf = (kt + 2 < NT);
        // drain exactly tile kt's 6 loads; leave tile kt+1's in flight
        if (kt + 1 < NT) { WAITV(6); } else { WAITV(0); }
        BARRIER();
        const short* la = &lds[b * 24576];
        const short* lb = la + 8192;
        short8 vb0, vb1, vb2, vb3, va0, va1;
        // ---- phase 0: ks=0, acc rows 0,1 ----
        RD_B(vb0, 0, 0); RD_B(vb1, 1, 0); RD_B(vb2, 2, 0); RD_B(vb3, 3, 0);
        RD_A(va0, 0, 0); RD_A(va1, 1, 0);
        if (pf) STAGE_A(kt + 2, bnx);
        LGKM0(); SCHEDB();
        __builtin_amdgcn_s_setprio(1);
        MFMA4(0, va0); MFMA4(1, va1);
        __builtin_amdgcn_s_setprio(0); SCHEDB();
        BARRIER();
        // ---- phase 1: ks=0, acc rows 2,3 (B frags still live) ----
        RD_A(va0, 2, 0); RD_A(va1, 3, 0);
        if (pf) STAGE_B(kt + 2, bnx, 0);
        LGKM0(); SCHEDB();
        __builtin_amdgcn_s_setprio(1);
        MFMA4(2, va0); MFMA4(3, va1);
        __builtin_amdgcn_s_setprio(0); SCHEDB();
        BARRIER();
        // ---- phase 2: ks=1, acc rows 0,1 ----
        RD_B(vb0, 0, 1); RD_B(vb1, 1, 1); RD_B(vb2, 2, 1); RD_B(vb3, 3, 1);
        RD_A(va0, 0, 1); RD_A(va1, 1, 1);
        if (pf) STAGE_B(kt + 2, bnx, 2);
        LGKM0(); SCHEDB();
        __builtin_amdgcn_s_setprio(1);
        MFMA4(0, va0); MFMA4(1, va1);
        __builtin_amdgcn_s_setprio(0); SCHEDB();
        BARRIER();
        // ---- phase 3: ks=1, acc rows 2,3 ----
        RD_A(va0, 2, 1); RD_A(va1, 3, 1);
        LGKM0(); SCHEDB();
        __builtin_amdgcn_s_setprio(1);
        MFMA4(2, va0); MFMA4(3, va1);
        __builtin_amdgcn_s_setprio(0); SCHEDB();
        BARRIER();
    }
#undef STAGE_A
#undef STAGE_B
#undef RD_A
#undef RD_B
#undef MFMA4

#pragma unroll
    for (int mi = 0; mi < 4; ++mi) {
        int crow0 = m0 + wm * 64 + mi * 16 + kg * 4;
#pragma unroll
        for (int ni = 0; ni < 4; ++ni) {
            int ccol = n0 + wn * 64 + ni * 16 + lr;
#pragma unroll
            for (int i = 0; i < 4; ++i) {
                float v = acc[mi][ni][i];
                size_t crow = (size_t)(crow0 + i);
                if constexpr (EPI == P_GATE) {
                    // h (f32) | silu(gate) (bf16)
                    if (ccol < 4096) ((float*)C0v)[crow * 4096 + ccol] = v;
                    else {
                        float s = v / (1.f + __expf(-v));
                        ((unsigned short*)C1v)[crow * 4096 + (ccol - 4096)] = f2bf(s);
                    }
                } else {
                    // split-K partial plain stores: z=0,1 -> C0; z=2,3 -> C1
                    float* P = (float*)(blockIdx.z < 2 ? C0v : C1v) +
                               (size_t)(blockIdx.z & 1) * 1024 * 2048;
                    P[crow * N + ccol] = v;
                }
            }
        }
    }
}

// ---------------- 2-phase bf16 MFMA GEMM (GEMM2/3) ----------------
enum { EPI_PLAIN = 0, EPI_SPLIT = 1, EPI_ATOMIC = 2, EPI_SOFTPLUS = 3 };

template <int BM, int EPI>
__global__ __launch_bounds__(256)
void gemm_bt(const short* __restrict__ A, const short* __restrict__ B,
             float* __restrict__ C, float* __restrict__ C2,
             const float* __restrict__ bias,
             int M, int N, int K, int ldc, int kcLen) {
    __shared__ short A_lds[BM * 32];
    __shared__ short B_lds[128 * 32];
    const int tid = threadIdx.x;
    const int wv = tid >> 6, ln = tid & 63;
    const int lr = ln & 15, kg = ln >> 4;
    const int m0 = blockIdx.y * BM;
    const int n0 = blockIdx.x * 128;
    const int kbeg = blockIdx.z * kcLen;
    const int kend = kbeg + kcLen;
    const int wm = wv >> 1, wn = wv & 1;
    constexpr int MR = BM / 32;

    f32x4 acc[MR][4];
#pragma unroll
    for (int mi = 0; mi < MR; ++mi)
#pragma unroll
        for (int ni = 0; ni < 4; ++ni) acc[mi][ni] = (f32x4){0.f, 0.f, 0.f, 0.f};

    const int arow = tid >> 2;
    const int kq8 = (tid & 3) * 8;

    for (int k0 = kbeg; k0 < kend; k0 += 32) {
#pragma unroll
        for (int r = 0; r < BM / 64; ++r) {
            const short* srcA = A + (size_t)(m0 + r * 64 + arow) * K + (k0 + kq8);
            short* dstA = &A_lds[(r * 64 + wv * 16) * 32];
            __builtin_amdgcn_global_load_lds((const AS1 void*)srcA, (AS3 void*)dstA, 16, 0, 0);
        }
#pragma unroll
        for (int r = 0; r < 2; ++r) {
            int brow = n0 + r * 64 + arow;
            if (brow > N - 1) brow = N - 1;
            const short* srcB = B + (size_t)brow * K + (k0 + kq8);
            short* dstB = &B_lds[(r * 64 + wv * 16) * 32];
            __builtin_amdgcn_global_load_lds((const AS1 void*)srcB, (AS3 void*)dstB, 16, 0, 0);
        }
        __syncthreads();

        short8 av[MR], bv[4];
#pragma unroll
        for (int mi = 0; mi < MR; ++mi)
            av[mi] = *(const short8*)&A_lds[(wm * (BM / 2) + mi * 16 + lr) * 32 + kg * 8];
#pragma unroll
        for (int ni = 0; ni < 4; ++ni)
            bv[ni] = *(const short8*)&B_lds[(wn * 64 + ni * 16 + lr) * 32 + kg * 8];
#pragma unroll
        for (int mi = 0; mi < MR; ++mi)
#pragma unroll
            for (int ni = 0; ni < 4; ++ni)
                acc[mi][ni] = __builtin_amdgcn_mfma_f32_16x16x32_bf16(av[mi], bv[ni], acc[mi][ni], 0, 0, 0);
        __syncthreads();
    }

#pragma unroll
    for (int mi = 0; mi < MR; ++mi) {
        int crow0 = m0 + wm * (BM / 2) + mi * 16 + kg * 4;
#pragma unroll
        for (int ni = 0; ni < 4; ++ni) {
            int ccol = n0 + wn * 64 + ni * 16 + lr;
#pragma unroll
            for (int i = 0; i < 4; ++i) {
                float v = acc[mi][ni][i];
                size_t crow = (size_t)(crow0 + i);
                if constexpr (EPI == EPI_PLAIN) {
                    C[crow * ldc + ccol] = v;
                } else if constexpr (EPI == EPI_SPLIT) {
                    if (ccol < 4096) C[crow * 4096 + ccol] = v;
                    else C2[crow * 4096 + (ccol - 4096)] = v;
                } else if constexpr (EPI == EPI_ATOMIC) {
                    if (ccol < N) atomicAdd(&C[crow * ldc + ccol], v);
                } else {   // EPI_SOFTPLUS: bf16 softplus(v + bias[n]) -> dt
                    float x = v + bias[ccol];
                    float sp = fmaxf(x, 0.f) + log1pf(__expf(-fabsf(x)));
                    ((unsigned short*)C)[crow * ldc + ccol] = f2bf(sp);
                }
            }
        }
    }
}

// ================= chunked selective scan (bf16 dt/hc/gate) =================
#define CLEN 16
#define NCH 64

__global__ __launch_bounds__(256)
void scan_p1(const unsigned short* __restrict__ dt, const unsigned short* __restrict__ hc,
             const float* __restrict__ ssmp, const float* __restrict__ A_log,
             float* __restrict__ Sbuf, float* __restrict__ dtsum) {
    const int tid = threadIdx.x;
    const int c = blockIdx.x & (NCH - 1);
    const int db = blockIdx.x >> 6;
    const int d = db * 256 + tid;
    const int t0 = c * CLEN;

    float Ac[16];
#pragma unroll
    for (int i = 0; i < 4; ++i) {
        float4 v = *(const float4*)&A_log[d * 16 + i * 4];
        Ac[i*4+0] = -__expf(v.x); Ac[i*4+1] = -__expf(v.y);
        Ac[i*4+2] = -__expf(v.z); Ac[i*4+3] = -__expf(v.w);
    }

    __shared__ float sB[CLEN][16];
    sB[tid >> 4][tid & 15] = ssmp[(t0 + (tid >> 4)) * 160 + 128 + (tid & 15)];
    __syncthreads();

    float st[16];
#pragma unroll
    for (int n = 0; n < 16; ++n) st[n] = 0.f;
    float ds = 0.f;

    for (int tt = 0; tt < CLEN; ++tt) {
        size_t g = (size_t)(t0 + tt) * 4096 + d;
        float dtv = bf2f(dt[g]);
        float hcv = bf2f(hc[g]);
        float du = dtv * hcv;
        ds += dtv;
#pragma unroll
        for (int n = 0; n < 16; ++n) {
            float dA = __expf(dtv * Ac[n]);
            st[n] = fmaf(dA, st[n], du * sB[tt][n]);
        }
    }

    float* o = Sbuf + ((size_t)c * 4096 + d) * 16;
#pragma unroll
    for (int i = 0; i < 4; ++i)
        *(float4*)&o[i * 4] = make_float4(st[i*4], st[i*4+1], st[i*4+2], st[i*4+3]);
    dtsum[c * 4096 + d] = ds;
}

__global__ __launch_bounds__(256)
void scan_p2(const float* __restrict__ A_log, const float* __restrict__ dtsum,
             float* __restrict__ S) {
    const int idx = blockIdx.x * 256 + threadIdx.x;   // (d,n), 65536
    const int d = idx >> 4;
    const float Ac = -__expf(A_log[idx]);

    float sl[NCH], Pv[NCH];
#pragma unroll
    for (int c = 0; c < NCH; ++c) sl[c] = S[(size_t)c * 65536 + idx];
#pragma unroll
    for (int c = 0; c < NCH; ++c) Pv[c] = __expf(Ac * dtsum[c * 4096 + d]);

    float s = 0.f;
#pragma unroll
    for (int c = 0; c < NCH; ++c) {
        S[(size_t)c * 65536 + idx] = s;
        s = fmaf(Pv[c], s, sl[c]);
    }
}

__global__ __launch_bounds__(256)
void scan_p3(const unsigned short* __restrict__ dt, const unsigned short* __restrict__ hc,
             const float* __restrict__ ssmp, const float* __restrict__ A_log,
             const float* __restrict__ Dp, const unsigned short* __restrict__ gate,
             const float* __restrict__ Sinit, unsigned short* __restrict__ y_bf) {
    const int tid = threadIdx.x;
    const int c = blockIdx.x & (NCH - 1);
    const int db = blockIdx.x >> 6;
    const int d = db * 256 + tid;
    const int t0 = c * CLEN;

    float Ac[16];
#pragma unroll
    for (int i = 0; i < 4; ++i) {
        float4 v = *(const float4*)&A_log[d * 16 + i * 4];
        Ac[i*4+0] = -__expf(v.x); Ac[i*4+1] = -__expf(v.y);
        Ac[i*4+2] = -__expf(v.z); Ac[i*4+3] = -__expf(v.w);
    }
    const float Dcoef = Dp[d];

    __shared__ float sB[CLEN][16], sC[CLEN][16];
    {
        int tt = tid >> 4, nn = tid & 15;
        sB[tt][nn] = ssmp[(t0 + tt) * 160 + 128 + nn];
        sC[tt][nn] = ssmp[(t0 + tt) * 160 + 144 + nn];
    }
    __syncthreads();

    float st[16];
    {
        const float* si = Sinit + ((size_t)c * 4096 + d) * 16;
#pragma unroll
        for (int i = 0; i < 4; ++i) {
            float4 v = *(const float4*)&si[i * 4];
            st[i*4] = v.x; st[i*4+1] = v.y; st[i*4+2] = v.z; st[i*4+3] = v.w;
        }
    }

    for (int tt = 0; tt < CLEN; ++tt) {
        size_t g = (size_t)(t0 + tt) * 4096 + d;
        float dtv = bf2f(dt[g]);
        float hcv = bf2f(hc[g]);
        float du = dtv * hcv;
        float p[16];
#pragma unroll
        for (int n = 0; n < 16; ++n) {
            float dA = __expf(dtv * Ac[n]);
            st[n] = fmaf(dA, st[n], du * sB[tt][n]);
            p[n] = st[n] * sC[tt][n];
        }
#pragma unroll
        for (int n = 0; n < 8; ++n) p[n] += p[n + 8];
#pragma unroll
        for (int n = 0; n < 4; ++n) p[n] += p[n + 4];
        p[0] += p[2]; p[1] += p[3];
        float csum = p[0] + p[1];
        float gv = bf2f(gate[g]);   // already silu'd
        float yv = (csum + hcv * Dcoef) * gv;
        y_bf[g] = f2bf(yv);
    }
}

// ---------------- launch ----------------
extern "C" void kernel_launch(void* const* d_in, const int* in_sizes, int n_in,
                              void* d_out, int out_size, void* d_ws, size_t ws_size,
                              hipStream_t stream) {
    (void)in_sizes; (void)n_in; (void)out_size; (void)ws_size;
    const float* hidden = (const float*)d_in[0];
    const float* W_in   = (const float*)d_in[1];
    const float* conv_w = (const float*)d_in[2];
    const float* conv_b = (const float*)d_in[3];
    const float* W_x    = (const float*)d_in[4];
    const float* W_dt   = (const float*)d_in[5];
    const float* b_dt   = (const float*)d_in[6];
    const float* A_log  = (const float*)d_in[7];
    const float* D_p    = (const float*)d_in[8];
    const float* W_out  = (const float*)d_in[9];
    float* out = (float*)d_out;

    char* w = (char*)d_ws;
    unsigned short* hid_bf = (unsigned short*)w;  w += (size_t)1024 * 2048 * 2;
    unsigned short* Wbig   = (unsigned short*)w;  w += (size_t)8192 * 2048 * 2;
    float* h_buf           = (float*)w;           w += (size_t)1024 * 4096 * 4;  // h f32; later GEMM4 partials z2,z3
    unsigned short* gate_bf= (unsigned short*)w;  w += (size_t)1024 * 4096 * 2;  // silu(gate) bf16
    unsigned short* hc_bf  = (unsigned short*)w;  w += (size_t)1024 * 4096 * 2;
    unsigned short* dt_bf  = (unsigned short*)w;  w += (size_t)1024 * 4096 * 2;
    float* ssmp            = (float*)w;           w += (size_t)1024 * 160 * 4;
    unsigned short* ts_bf  = (unsigned short*)w;  w += (size_t)1024 * 128 * 2;
    unsigned short* Wx_bf  = (unsigned short*)w;  w += (size_t)160 * 4096 * 2;
    unsigned short* Wdt_bf = (unsigned short*)w;  w += (size_t)4096 * 128 * 2;
    unsigned short* y_bf   = (unsigned short*)w;  w += (size_t)1024 * 4096 * 2;
    float* Sbuf            = (float*)w;           w += (size_t)NCH * 4096 * 16 * 4; // scan states; later GEMM4 partials z0,z1
    float* dtsum           = (float*)w;           w += (size_t)NCH * 4096 * 4;

    hipMemsetAsync(ssmp, 0, (size_t)1024 * 160 * 4, stream);   // GEMM2 atomic target

    cvt_f32_bf16<<<2048, 256, 0, stream>>>(hidden, hid_bf, 1024 * 2048 / 4);
    cvt_f32_bf16<<<4096, 256, 0, stream>>>(W_in, Wbig, 8192 * 2048 / 4);
    cvt_f32_bf16<<<640, 256, 0, stream>>>(W_x, Wx_bf, 160 * 4096 / 4);
    cvt_f32_bf16<<<512, 256, 0, stream>>>(W_dt, Wdt_bf, 4096 * 128 / 4);

    // GEMM1: proj = hidden @ W_in^T -> h (f32) | silu(gate) (bf16)
    gemm8p<P_GATE><<<dim3(256, 1, 1), 512, 0, stream>>>(
        (const short*)hid_bf, (const short*)Wbig, h_buf, gate_bf, 8192, 2048, 2048);

    conv_silu<<<16384, 256, 0, stream>>>(h_buf, conv_w, conv_b, hc_bf);

    cvt_f32_bf16<<<2048, 256, 0, stream>>>(W_out, Wbig, 2048 * 4096 / 4);

    gemm_bt<128, EPI_ATOMIC><<<dim3(2, 8, 16), 256, 0, stream>>>(
        (const short*)hc_bf, (const short*)Wx_bf, ssmp, nullptr, nullptr,
        1024, 160, 4096, 160, 256);

    cvt_ts<<<128, 256, 0, stream>>>(ssmp, ts_bf);

    // GEMM3: dt = softplus(ts @ W_dt^T + b_dt) -> bf16
    gemm_bt<128, EPI_SOFTPLUS><<<dim3(32, 8, 1), 256, 0, stream>>>(
        (const short*)ts_bf, (const short*)Wdt_bf, (float*)dt_bf, nullptr, b_dt,
        1024, 4096, 128, 4096, 128);

    scan_p1<<<NCH * 16, 256, 0, stream>>>(dt_bf, hc_bf, ssmp, A_log, Sbuf, dtsum);
    scan_p2<<<256, 256, 0, stream>>>(A_log, dtsum, Sbuf);
    scan_p3<<<NCH * 16, 256, 0, stream>>>(dt_bf, hc_bf, ssmp, A_log, D_p, gate_bf, Sbuf, y_bf);

    // GEMM4: out = y @ W_out^T — split-K x4, plain-store partials into dead
    // Sbuf (z=0,1) / h_buf (z=2,3), then vectorized reduce.
    gemm8p<P_PART><<<dim3(64, 1, 4), 512, 0, stream>>>(
        (const short*)y_bf, (const short*)Wbig, Sbuf, h_buf, 2048, 4096, 1024);
    reduce4<<<2048, 256, 0, stream>>>(Sbuf, h_buf, out, 1024 * 2048 / 4);
}

// Round 8
// 216.077 us; speedup vs baseline: 1.4823x; 1.0005x over previous
//
#include <hip/hip_runtime.h>
#include <math.h>

#define AS1 __attribute__((address_space(1)))
#define AS3 __attribute__((address_space(3)))

typedef __attribute__((ext_vector_type(8))) short short8;
typedef __attribute__((ext_vector_type(4))) float f32x4;

#define WAITV(n) asm volatile("s_waitcnt vmcnt(" #n ")" ::: "memory")
#define BARRIER() asm volatile("s_barrier" ::: "memory")

static __device__ __forceinline__ unsigned short f2bf(float f) {
    unsigned u = __float_as_uint(f);
    unsigned r = (u + 0x7fffu + ((u >> 16) & 1u)) >> 16;
    return (unsigned short)r;
}
static __device__ __forceinline__ float bf2f(unsigned short u) {
    return __uint_as_float(((unsigned)u) << 16);
}

// ---------------- f32 -> bf16 convert (vectorized x4) ----------------
__global__ __launch_bounds__(256) void cvt_f32_bf16(const float* __restrict__ src,
                                                    unsigned short* __restrict__ dst,
                                                    int n4) {
    int i = blockIdx.x * 256 + threadIdx.x;
    int stride = gridDim.x * 256;
    for (; i < n4; i += stride) {
        float4 v = ((const float4*)src)[i];
        ushort4 o;
        o.x = f2bf(v.x); o.y = f2bf(v.y); o.z = f2bf(v.z); o.w = f2bf(v.w);
        ((ushort4*)dst)[i] = o;
    }
}

// extract ts (cols 0..127 of ssm_p, row stride 160) -> dense bf16 1024x128
__global__ __launch_bounds__(256) void cvt_ts(const float* __restrict__ ssmp,
                                              unsigned short* __restrict__ ts) {
    int i = blockIdx.x * 256 + threadIdx.x;   // < 32768
    int t = i >> 5, c4 = (i & 31) * 4;
    float4 v = *(const float4*)&ssmp[t * 160 + c4];
    ushort4 o;
    o.x = f2bf(v.x); o.y = f2bf(v.y); o.z = f2bf(v.z); o.w = f2bf(v.w);
    *(ushort4*)&ts[t * 128 + c4] = o;
}

// ------- depthwise causal conv (K=4) + bias + silu -> hc bf16 only -------
__global__ __launch_bounds__(256) void conv_silu(const float* __restrict__ h,
                                                 const float* __restrict__ cw,
                                                 const float* __restrict__ cb,
                                                 unsigned short* __restrict__ hc_bf) {
    int idx = blockIdx.x * 256 + threadIdx.x;   // < 1024*4096
    int d = idx & 4095, t = idx >> 12;
    float acc = cb[d];
    float4 w = *(const float4*)&cw[d * 4];
    const float* wp = (const float*)&w;
#pragma unroll
    for (int k = 0; k < 4; ++k) {
        int tt = t + k - 3;
        if (tt >= 0) acc += h[tt * 4096 + d] * wp[k];
    }
    float s = acc / (1.f + __expf(-acc));   // silu
    hc_bf[idx] = f2bf(s);
}

// ---------------- reduce 4 split-K partials -> out ----------------
__global__ __launch_bounds__(256) void reduce4(const float* __restrict__ pA,
                                               const float* __restrict__ pB,
                                               float* __restrict__ out, int n4) {
    int i = blockIdx.x * 256 + threadIdx.x;
    int stride = gridDim.x * 256;
    const size_t MN4 = (size_t)1024 * 2048 / 4;
    for (; i < n4; i += stride) {
        float4 a = ((const float4*)pA)[i];
        float4 b = ((const float4*)pA)[i + MN4];
        float4 c = ((const float4*)pB)[i];
        float4 d = ((const float4*)pB)[i + MN4];
        float4 o;
        o.x = (a.x + b.x) + (c.x + d.x);
        o.y = (a.y + b.y) + (c.y + d.y);
        o.z = (a.z + b.z) + (c.z + d.z);
        o.w = (a.w + b.w) + (c.w + d.w);
        ((float4*)out)[i] = o;
    }
}

// ======== pipelined bf16 MFMA GEMM: C(M,N)=A(M,K)@B(N,K)^T ========
// BM=128, BN=256, BK=64. 512 threads = 8 waves (2M x 4N), wave tile 64x64.
// 3-buffer LDS rotation (144KB), prefetch depth 2, counted vmcnt(6) (never
// 0 in steady state). ONE s_barrier per K-tile: staging at iter kt writes
// buf (kt+2)%3 == (kt-1)%3, and the top-of-tile barrier guarantees every
// wave finished tile kt-1 — no intra-tile barriers/lgkm drains needed; the
// compiler schedules ds_read->MFMA with fine-grained lgkmcnt and pipelines
// ks1 reads under ks0 MFMAs. XOR-swizzled LDS via pre-swizzled global
// source (linear dest, rule 21). setprio around MFMA clusters.
// XCD-bijective block swizzle. M fixed = 1024.
enum { P_GATE = 0, P_PART = 1 };

template <int EPI>
__global__ __launch_bounds__(512, 2)
void gemm8p(const short* __restrict__ A, const short* __restrict__ B,
            void* __restrict__ C0v, void* __restrict__ C1v,
            int N, int K, int kchunk) {
    __shared__ short lds[3 * 24576];   // per buf: A 128x64 (8192) + B 256x64 (16384)

    const int tid = threadIdx.x;
    const int wv = tid >> 6, ln = tid & 63;
    const int lr = ln & 15, kg = ln >> 4;
    const int wm = wv >> 2, wn = wv & 3;

    const int nwg = gridDim.x;
    const int bid = blockIdx.x;
    const int swz = (bid & 7) * (nwg >> 3) + (bid >> 3);   // nwg % 8 == 0
    const int by = swz & 7, bx = swz >> 3;
    const int m0 = by * 128;
    const int n0 = bx * 256;
    const int kbeg = blockIdx.z * kchunk;
    const int NT = kchunk >> 6;

    f32x4 acc[4][4];
#pragma unroll
    for (int mi = 0; mi < 4; ++mi)
#pragma unroll
        for (int ni = 0; ni < 4; ++ni) acc[mi][ni] = (f32x4){0.f, 0.f, 0.f, 0.f};

    const short* Abase = A + (size_t)m0 * K + kbeg;
    const short* Bbase = B + (size_t)n0 * K + kbeg;

// source column pre-swizzled so LDS[row][byte j] = Global[row][byte j ^ ((row&7)<<4)]
#define STAGE(kt, b)                                                          \
    {                                                                         \
        short* lbase = &lds[(b) * 24576];                                     \
        _Pragma("unroll")                                                     \
        for (int r = 0; r < 2; ++r) {                                         \
            int c = r * 512 + tid;                                            \
            int row = c >> 3, cb8 = (c & 7) << 4;                             \
            int scb = cb8 ^ ((row & 7) << 4);                                 \
            const short* src = Abase + (size_t)row * K + (kt) * 64 + (scb >> 1); \
            short* dst = lbase + (r * 512 + wv * 64) * 8;                     \
            __builtin_amdgcn_global_load_lds((const AS1 void*)src,            \
                                             (AS3 void*)dst, 16, 0, 0);       \
        }                                                                     \
        _Pragma("unroll")                                                     \
        for (int r = 0; r < 4; ++r) {                                         \
            int c = r * 512 + tid;                                            \
            int row = c >> 3, cb8 = (c & 7) << 4;                             \
            int scb = cb8 ^ ((row & 7) << 4);                                 \
            const short* src = Bbase + (size_t)row * K + (kt) * 64 + (scb >> 1); \
            short* dst = lbase + 8192 + (r * 512 + wv * 64) * 8;              \
            __builtin_amdgcn_global_load_lds((const AS1 void*)src,            \
                                             (AS3 void*)dst, 16, 0, 0);       \
        }                                                                     \
    }
#define RD_A(dst, mi, ks)                                                     \
    { int row = wm * 64 + (mi) * 16 + lr;                                     \
      int col = ((ks) * 32 + kg * 8) ^ ((row & 7) << 3);                      \
      dst = *(const short8*)&la[row * 64 + col]; }
#define RD_B(dst, ni, ks)                                                     \
    { int row = wn * 64 + (ni) * 16 + lr;                                     \
      int col = ((ks) * 32 + kg * 8) ^ ((row & 7) << 3);                      \
      dst = *(const short8*)&lb[row * 64 + col]; }
#define MFMA4(mi, a)                                                          \
    acc[mi][0] = __builtin_amdgcn_mfma_f32_16x16x32_bf16(a, vb0, acc[mi][0], 0, 0, 0); \
    acc[mi][1] = __builtin_amdgcn_mfma_f32_16x16x32_bf16(a, vb1, acc[mi][1], 0, 0, 0); \
    acc[mi][2] = __builtin_amdgcn_mfma_f32_16x16x32_bf16(a, vb2, acc[mi][2], 0, 0, 0); \
    acc[mi][3] = __builtin_amdgcn_mfma_f32_16x16x32_bf16(a, vb3, acc[mi][3], 0, 0, 0);

    // prologue: fully stage tiles 0 and 1
    STAGE(0, 0);
    STAGE(1, 1);

    for (int kt = 0; kt < NT; ++kt) {
        const int b = kt % 3;
        // drain exactly tile kt's 6 loads; tile kt+1's stay in flight
        if (kt + 1 < NT) { WAITV(6); } else { WAITV(0); }
        BARRIER();   // buf b staged for all waves; all waves past tile kt-1
        // prefetch tile kt+2 into buf (kt+2)%3 == (kt-1)%3 (safe: barrier above)
        if (kt + 2 < NT) STAGE(kt + 2, (kt + 2) % 3);

        const short* la = &lds[b * 24576];
        const short* lb = la + 8192;
        short8 va0, va1, va2, va3, vb0, vb1, vb2, vb3;
        // ks = 0 : 8 ds_read + 16 MFMA
        RD_B(vb0, 0, 0); RD_B(vb1, 1, 0); RD_B(vb2, 2, 0); RD_B(vb3, 3, 0);
        RD_A(va0, 0, 0); RD_A(va1, 1, 0); RD_A(va2, 2, 0); RD_A(va3, 3, 0);
        __builtin_amdgcn_s_setprio(1);
        MFMA4(0, va0); MFMA4(1, va1); MFMA4(2, va2); MFMA4(3, va3);
        __builtin_amdgcn_s_setprio(0);
        // ks = 1 : 8 ds_read + 16 MFMA (compiler pipelines these reads
        // under the ks=0 MFMAs; no barrier/drain needed within the tile)
        RD_B(vb0, 0, 1); RD_B(vb1, 1, 1); RD_B(vb2, 2, 1); RD_B(vb3, 3, 1);
        RD_A(va0, 0, 1); RD_A(va1, 1, 1); RD_A(va2, 2, 1); RD_A(va3, 3, 1);
        __builtin_amdgcn_s_setprio(1);
        MFMA4(0, va0); MFMA4(1, va1); MFMA4(2, va2); MFMA4(3, va3);
        __builtin_amdgcn_s_setprio(0);
    }
#undef STAGE
#undef RD_A
#undef RD_B
#undef MFMA4

#pragma unroll
    for (int mi = 0; mi < 4; ++mi) {
        int crow0 = m0 + wm * 64 + mi * 16 + kg * 4;
#pragma unroll
        for (int ni = 0; ni < 4; ++ni) {
            int ccol = n0 + wn * 64 + ni * 16 + lr;
#pragma unroll
            for (int i = 0; i < 4; ++i) {
                float v = acc[mi][ni][i];
                size_t crow = (size_t)(crow0 + i);
                if constexpr (EPI == P_GATE) {
                    // h (f32) | silu(gate) (bf16)
                    if (ccol < 4096) ((float*)C0v)[crow * 4096 + ccol] = v;
                    else {
                        float s = v / (1.f + __expf(-v));
                        ((unsigned short*)C1v)[crow * 4096 + (ccol - 4096)] = f2bf(s);
                    }
                } else {
                    // split-K partial plain stores: z=0,1 -> C0; z=2,3 -> C1
                    float* P = (float*)(blockIdx.z < 2 ? C0v : C1v) +
                               (size_t)(blockIdx.z & 1) * 1024 * 2048;
                    P[crow * N + ccol] = v;
                }
            }
        }
    }
}

// ---------------- 2-phase bf16 MFMA GEMM (GEMM2/3) ----------------
enum { EPI_PLAIN = 0, EPI_SPLIT = 1, EPI_ATOMIC = 2, EPI_SOFTPLUS = 3 };

template <int BM, int EPI>
__global__ __launch_bounds__(256)
void gemm_bt(const short* __restrict__ A, const short* __restrict__ B,
             float* __restrict__ C, float* __restrict__ C2,
             const float* __restrict__ bias,
             int M, int N, int K, int ldc, int kcLen) {
    __shared__ short A_lds[BM * 32];
    __shared__ short B_lds[128 * 32];
    const int tid = threadIdx.x;
    const int wv = tid >> 6, ln = tid & 63;
    const int lr = ln & 15, kg = ln >> 4;
    const int m0 = blockIdx.y * BM;
    const int n0 = blockIdx.x * 128;
    const int kbeg = blockIdx.z * kcLen;
    const int kend = kbeg + kcLen;
    const int wm = wv >> 1, wn = wv & 1;
    constexpr int MR = BM / 32;

    f32x4 acc[MR][4];
#pragma unroll
    for (int mi = 0; mi < MR; ++mi)
#pragma unroll
        for (int ni = 0; ni < 4; ++ni) acc[mi][ni] = (f32x4){0.f, 0.f, 0.f, 0.f};

    const int arow = tid >> 2;
    const int kq8 = (tid & 3) * 8;

    for (int k0 = kbeg; k0 < kend; k0 += 32) {
#pragma unroll
        for (int r = 0; r < BM / 64; ++r) {
            const short* srcA = A + (size_t)(m0 + r * 64 + arow) * K + (k0 + kq8);
            short* dstA = &A_lds[(r * 64 + wv * 16) * 32];
            __builtin_amdgcn_global_load_lds((const AS1 void*)srcA, (AS3 void*)dstA, 16, 0, 0);
        }
#pragma unroll
        for (int r = 0; r < 2; ++r) {
            int brow = n0 + r * 64 + arow;
            if (brow > N - 1) brow = N - 1;
            const short* srcB = B + (size_t)brow * K + (k0 + kq8);
            short* dstB = &B_lds[(r * 64 + wv * 16) * 32];
            __builtin_amdgcn_global_load_lds((const AS1 void*)srcB, (AS3 void*)dstB, 16, 0, 0);
        }
        __syncthreads();

        short8 av[MR], bv[4];
#pragma unroll
        for (int mi = 0; mi < MR; ++mi)
            av[mi] = *(const short8*)&A_lds[(wm * (BM / 2) + mi * 16 + lr) * 32 + kg * 8];
#pragma unroll
        for (int ni = 0; ni < 4; ++ni)
            bv[ni] = *(const short8*)&B_lds[(wn * 64 + ni * 16 + lr) * 32 + kg * 8];
#pragma unroll
        for (int mi = 0; mi < MR; ++mi)
#pragma unroll
            for (int ni = 0; ni < 4; ++ni)
                acc[mi][ni] = __builtin_amdgcn_mfma_f32_16x16x32_bf16(av[mi], bv[ni], acc[mi][ni], 0, 0, 0);
        __syncthreads();
    }

#pragma unroll
    for (int mi = 0; mi < MR; ++mi) {
        int crow0 = m0 + wm * (BM / 2) + mi * 16 + kg * 4;
#pragma unroll
        for (int ni = 0; ni < 4; ++ni) {
            int ccol = n0 + wn * 64 + ni * 16 + lr;
#pragma unroll
            for (int i = 0; i < 4; ++i) {
                float v = acc[mi][ni][i];
                size_t crow = (size_t)(crow0 + i);
                if constexpr (EPI == EPI_PLAIN) {
                    C[crow * ldc + ccol] = v;
                } else if constexpr (EPI == EPI_SPLIT) {
                    if (ccol < 4096) C[crow * 4096 + ccol] = v;
                    else C2[crow * 4096 + (ccol - 4096)] = v;
                } else if constexpr (EPI == EPI_ATOMIC) {
                    if (ccol < N) atomicAdd(&C[crow * ldc + ccol], v);
                } else {   // EPI_SOFTPLUS: bf16 softplus(v + bias[n]) -> dt
                    float x = v + bias[ccol];
                    float sp = fmaxf(x, 0.f) + log1pf(__expf(-fabsf(x)));
                    ((unsigned short*)C)[crow * ldc + ccol] = f2bf(sp);
                }
            }
        }
    }
}

// ================= chunked selective scan (bf16 dt/hc/gate) =================
#define CLEN 16
#define NCH 64

__global__ __launch_bounds__(256)
void scan_p1(const unsigned short* __restrict__ dt, const unsigned short* __restrict__ hc,
             const float* __restrict__ ssmp, const float* __restrict__ A_log,
             float* __restrict__ Sbuf, float* __restrict__ dtsum) {
    const int tid = threadIdx.x;
    const int c = blockIdx.x & (NCH - 1);
    const int db = blockIdx.x >> 6;
    const int d = db * 256 + tid;
    const int t0 = c * CLEN;

    float Ac[16];
#pragma unroll
    for (int i = 0; i < 4; ++i) {
        float4 v = *(const float4*)&A_log[d * 16 + i * 4];
        Ac[i*4+0] = -__expf(v.x); Ac[i*4+1] = -__expf(v.y);
        Ac[i*4+2] = -__expf(v.z); Ac[i*4+3] = -__expf(v.w);
    }

    __shared__ float sB[CLEN][16];
    sB[tid >> 4][tid & 15] = ssmp[(t0 + (tid >> 4)) * 160 + 128 + (tid & 15)];
    __syncthreads();

    float st[16];
#pragma unroll
    for (int n = 0; n < 16; ++n) st[n] = 0.f;
    float ds = 0.f;

    for (int tt = 0; tt < CLEN; ++tt) {
        size_t g = (size_t)(t0 + tt) * 4096 + d;
        float dtv = bf2f(dt[g]);
        float hcv = bf2f(hc[g]);
        float du = dtv * hcv;
        ds += dtv;
#pragma unroll
        for (int n = 0; n < 16; ++n) {
            float dA = __expf(dtv * Ac[n]);
            st[n] = fmaf(dA, st[n], du * sB[tt][n]);
        }
    }

    float* o = Sbuf + ((size_t)c * 4096 + d) * 16;
#pragma unroll
    for (int i = 0; i < 4; ++i)
        *(float4*)&o[i * 4] = make_float4(st[i*4], st[i*4+1], st[i*4+2], st[i*4+3]);
    dtsum[c * 4096 + d] = ds;
}

__global__ __launch_bounds__(256)
void scan_p2(const float* __restrict__ A_log, const float* __restrict__ dtsum,
             float* __restrict__ S) {
    const int idx = blockIdx.x * 256 + threadIdx.x;   // (d,n), 65536
    const int d = idx >> 4;
    const float Ac = -__expf(A_log[idx]);

    float sl[NCH], Pv[NCH];
#pragma unroll
    for (int c = 0; c < NCH; ++c) sl[c] = S[(size_t)c * 65536 + idx];
#pragma unroll
    for (int c = 0; c < NCH; ++c) Pv[c] = __expf(Ac * dtsum[c * 4096 + d]);

    float s = 0.f;
#pragma unroll
    for (int c = 0; c < NCH; ++c) {
        S[(size_t)c * 65536 + idx] = s;
        s = fmaf(Pv[c], s, sl[c]);
    }
}

__global__ __launch_bounds__(256)
void scan_p3(const unsigned short* __restrict__ dt, const unsigned short* __restrict__ hc,
             const float* __restrict__ ssmp, const float* __restrict__ A_log,
             const float* __restrict__ Dp, const unsigned short* __restrict__ gate,
             const float* __restrict__ Sinit, unsigned short* __restrict__ y_bf) {
    const int tid = threadIdx.x;
    const int c = blockIdx.x & (NCH - 1);
    const int db = blockIdx.x >> 6;
    const int d = db * 256 + tid;
    const int t0 = c * CLEN;

    float Ac[16];
#pragma unroll
    for (int i = 0; i < 4; ++i) {
        float4 v = *(const float4*)&A_log[d * 16 + i * 4];
        Ac[i*4+0] = -__expf(v.x); Ac[i*4+1] = -__expf(v.y);
        Ac[i*4+2] = -__expf(v.z); Ac[i*4+3] = -__expf(v.w);
    }
    const float Dcoef = Dp[d];

    __shared__ float sB[CLEN][16], sC[CLEN][16];
    {
        int tt = tid >> 4, nn = tid & 15;
        sB[tt][nn] = ssmp[(t0 + tt) * 160 + 128 + nn];
        sC[tt][nn] = ssmp[(t0 + tt) * 160 + 144 + nn];
    }
    __syncthreads();

    float st[16];
    {
        const float* si = Sinit + ((size_t)c * 4096 + d) * 16;
#pragma unroll
        for (int i = 0; i < 4; ++i) {
            float4 v = *(const float4*)&si[i * 4];
            st[i*4] = v.x; st[i*4+1] = v.y; st[i*4+2] = v.z; st[i*4+3] = v.w;
        }
    }

    for (int tt = 0; tt < CLEN; ++tt) {
        size_t g = (size_t)(t0 + tt) * 4096 + d;
        float dtv = bf2f(dt[g]);
        float hcv = bf2f(hc[g]);
        float du = dtv * hcv;
        float p[16];
#pragma unroll
        for (int n = 0; n < 16; ++n) {
            float dA = __expf(dtv * Ac[n]);
            st[n] = fmaf(dA, st[n], du * sB[tt][n]);
            p[n] = st[n] * sC[tt][n];
        }
#pragma unroll
        for (int n = 0; n < 8; ++n) p[n] += p[n + 8];
#pragma unroll
        for (int n = 0; n < 4; ++n) p[n] += p[n + 4];
        p[0] += p[2]; p[1] += p[3];
        float csum = p[0] + p[1];
        float gv = bf2f(gate[g]);   // already silu'd
        float yv = (csum + hcv * Dcoef) * gv;
        y_bf[g] = f2bf(yv);
    }
}

// ---------------- launch ----------------
extern "C" void kernel_launch(void* const* d_in, const int* in_sizes, int n_in,
                              void* d_out, int out_size, void* d_ws, size_t ws_size,
                              hipStream_t stream) {
    (void)in_sizes; (void)n_in; (void)out_size; (void)ws_size;
    const float* hidden = (const float*)d_in[0];
    const float* W_in   = (const float*)d_in[1];
    const float* conv_w = (const float*)d_in[2];
    const float* conv_b = (const float*)d_in[3];
    const float* W_x    = (const float*)d_in[4];
    const float* W_dt   = (const float*)d_in[5];
    const float* b_dt   = (const float*)d_in[6];
    const float* A_log  = (const float*)d_in[7];
    const float* D_p    = (const float*)d_in[8];
    const float* W_out  = (const float*)d_in[9];
    float* out = (float*)d_out;

    char* w = (char*)d_ws;
    unsigned short* hid_bf = (unsigned short*)w;  w += (size_t)1024 * 2048 * 2;
    unsigned short* Wbig   = (unsigned short*)w;  w += (size_t)8192 * 2048 * 2;
    float* h_buf           = (float*)w;           w += (size_t)1024 * 4096 * 4;  // h f32; later GEMM4 partials z2,z3
    unsigned short* gate_bf= (unsigned short*)w;  w += (size_t)1024 * 4096 * 2;  // silu(gate) bf16
    unsigned short* hc_bf  = (unsigned short*)w;  w += (size_t)1024 * 4096 * 2;
    unsigned short* dt_bf  = (unsigned short*)w;  w += (size_t)1024 * 4096 * 2;
    float* ssmp            = (float*)w;           w += (size_t)1024 * 160 * 4;
    unsigned short* ts_bf  = (unsigned short*)w;  w += (size_t)1024 * 128 * 2;
    unsigned short* Wx_bf  = (unsigned short*)w;  w += (size_t)160 * 4096 * 2;
    unsigned short* Wdt_bf = (unsigned short*)w;  w += (size_t)4096 * 128 * 2;
    unsigned short* y_bf   = (unsigned short*)w;  w += (size_t)1024 * 4096 * 2;
    float* Sbuf            = (float*)w;           w += (size_t)NCH * 4096 * 16 * 4; // scan states; later GEMM4 partials z0,z1
    float* dtsum           = (float*)w;           w += (size_t)NCH * 4096 * 4;

    hipMemsetAsync(ssmp, 0, (size_t)1024 * 160 * 4, stream);   // GEMM2 atomic target

    cvt_f32_bf16<<<2048, 256, 0, stream>>>(hidden, hid_bf, 1024 * 2048 / 4);
    cvt_f32_bf16<<<4096, 256, 0, stream>>>(W_in, Wbig, 8192 * 2048 / 4);
    cvt_f32_bf16<<<640, 256, 0, stream>>>(W_x, Wx_bf, 160 * 4096 / 4);
    cvt_f32_bf16<<<512, 256, 0, stream>>>(W_dt, Wdt_bf, 4096 * 128 / 4);

    // GEMM1: proj = hidden @ W_in^T -> h (f32) | silu(gate) (bf16)
    gemm8p<P_GATE><<<dim3(256, 1, 1), 512, 0, stream>>>(
        (const short*)hid_bf, (const short*)Wbig, h_buf, gate_bf, 8192, 2048, 2048);

    conv_silu<<<16384, 256, 0, stream>>>(h_buf, conv_w, conv_b, hc_bf);

    cvt_f32_bf16<<<2048, 256, 0, stream>>>(W_out, Wbig, 2048 * 4096 / 4);

    gemm_bt<128, EPI_ATOMIC><<<dim3(2, 8, 16), 256, 0, stream>>>(
        (const short*)hc_bf, (const short*)Wx_bf, ssmp, nullptr, nullptr,
        1024, 160, 4096, 160, 256);

    cvt_ts<<<128, 256, 0, stream>>>(ssmp, ts_bf);

    // GEMM3: dt = softplus(ts @ W_dt^T + b_dt) -> bf16
    gemm_bt<128, EPI_SOFTPLUS><<<dim3(32, 8, 1), 256, 0, stream>>>(
        (const short*)ts_bf, (const short*)Wdt_bf, (float*)dt_bf, nullptr, b_dt,
        1024, 4096, 128, 4096, 128);

    scan_p1<<<NCH * 16, 256, 0, stream>>>(dt_bf, hc_bf, ssmp, A_log, Sbuf, dtsum);
    scan_p2<<<256, 256, 0, stream>>>(A_log, dtsum, Sbuf);
    scan_p3<<<NCH * 16, 256, 0, stream>>>(dt_bf, hc_bf, ssmp, A_log, D_p, gate_bf, Sbuf, y_bf);

    // GEMM4: out = y @ W_out^T — split-K x4, plain-store partials into dead
    // Sbuf (z=0,1) / h_buf (z=2,3), then vectorized reduce.
    gemm8p<P_PART><<<dim3(64, 1, 4), 512, 0, stream>>>(
        (const short*)y_bf, (const short*)Wbig, Sbuf, h_buf, 2048, 4096, 1024);
    reduce4<<<2048, 256, 0, stream>>>(Sbuf, h_buf, out, 1024 * 2048 / 4);
}